// Round 11
// baseline (308.260 us; speedup 1.0000x reference)
//
#include <hip/hip_runtime.h>
#include <math.h>

#define MUL 32
#define NATTR 4
#define NBASIS 10
#define HID 64
#define OUT_DIM 16
#define NGRAPH 8
#define NT 513      // w(len) table entries: len = i/128, i in [0,512]

#define PI_F 3.14159265358979323846f
#define SQRT3_F 1.7320508075688772f
#define INV_SQRT3_F 0.5773502691896258f
#define INV_SQRT10_F 0.31622776601683794f
#define INV_SQRTNN_F 0.17677669529663687f   // 1/sqrt(32)
#define NORM128_F 0.08838834764831845f      // 1/sqrt(128)
#define NORM256_F 0.0625f                   // 1/sqrt(256)
#define C_S_F 0.3826834323650898f           // sin(pi/8)
#define C_X_F 0.9238795325112867f           // cos(pi/8)
#define CSTEP_F (4.0f/9.0f)                 // linspace(0,4,10) step

__device__ inline unsigned short f2bf(float x) {
    unsigned u = __float_as_uint(x);
    u += 0x7FFF + ((u >> 16) & 1);          // round-to-nearest-even
    return (unsigned short)(u >> 16);
}
__device__ inline float bf2f(unsigned short h) {
    return __uint_as_float(((unsigned)h) << 16);
}

// ---------------------------------------------------------------- bodies
__device__ __forceinline__ void init_sv_body(
    int blk, const float* __restrict__ x,
    float* __restrict__ s, float* __restrict__ v, int N) {
    int i = blk * 256 + threadIdx.x;
    if (i >= N * 128) return;
    int n = i >> 7, c = i & 127;
    float val = x[i];
    if (c < 32) s[n * 32 + c] = val;
    else        v[n * 96 + (c - 32)] = val;
}

__device__ __forceinline__ void setup_weights_body(
    int blk,
    const float* __restrict__ Wsc0, const float* __restrict__ Wl10,
    const float* __restrict__ Wsc1, const float* __restrict__ Wl11,
    const float* __restrict__ Wl20, const float* __restrict__ Wl21,
    float* __restrict__ Wfp, unsigned* __restrict__ Wupk) {
    int i = blk * 256 + threadIdx.x;
    if (i < 32768) {
        int idx = i >> 12;          // l*4 + m
        int r = i & 4095;
        int l = idx >> 2, m = idx & 3;
        const float* base = (m == 0 ? Wsc0 : m == 1 ? Wl10 : m == 2 ? Wsc1 : Wl11)
                            + l * 4096;
        int u = r >> 7, rr = r & 127, a = rr >> 5, ww = rr & 31;
        Wfp[idx * 4096 + u * 128 + ww * 4 + a] = base[r];
    } else if (i < 49152) {
        int j = i - 32768;
        int l = j >> 13;
        int r = j & 8191;
        int u = r >> 7, rr = r & 127, a = rr >> 5, ww = rr & 31;
        unsigned lo = f2bf(Wl20[l * 8192 + r]);
        unsigned hi = f2bf(Wl21[l * 8192 + r]);
        Wupk[l * 8192 + u * 128 + ww * 4 + a] = lo | (hi << 16);
    }
}

// w(len) table generator, cooperative: one 64-thread group per table row.
__device__ __forceinline__ void tab_gen_body(
    int blk, const float* __restrict__ Wfc1, const float* __restrict__ Wfc2,
    unsigned* __restrict__ tab, float (*sh_h)[64]) {
    int g = threadIdx.x >> 6;       // row group 0..3
    int n = threadIdx.x & 63;       // h index / output j
    int row = blk * 4 + g;
    bool valid = row < 2 * NT;
    int l = valid ? row / NT : 0;
    int i = valid ? row % NT : 0;
    float len = (float)i * (1.0f / 128.0f);
    float uu = len * 0.5f - 2.0f;
    float cut = (uu > 0.0f) ? 0.0f
              : ((uu < -1.0f) ? 1.0f : 0.5f * (1.0f - __cosf(PI_F * uu)));
    const float* W1 = Wfc1 + l * 640;
    float a = 0.f;
#pragma unroll
    for (int k = 0; k < 10; k++) {
        float d = (len - k * CSTEP_F) * 2.5f;
        float e = __expf(-d * d) * cut;
        a += e * W1[k * 64 + n];
    }
    a *= INV_SQRT10_F;
    sh_h[g][n] = a / (1.0f + __expf(-a));
    __syncthreads();
    if (!valid) return;
    const float* W2 = Wfc2 + l * 8192;
    float w0 = 0.f, w1 = 0.f;
#pragma unroll 8
    for (int nn = 0; nn < 64; nn++) {
        float hn = sh_h[g][nn];
        w0 += hn * W2[nn * 128 + n];
        w1 += hn * W2[nn * 128 + 64 + n];
    }
    w0 *= 0.125f; w1 *= 0.125f;
    tab[(size_t)l * NT * 64 + i * 64 + n] =
        (unsigned)f2bf(w0) | ((unsigned)f2bf(w1) << 16);
}

__device__ __forceinline__ void csr_count_body(
    int blk, const int* __restrict__ edst, int* __restrict__ cnt, int E) {
    int e = blk * 256 + threadIdx.x;
    if (e < E) atomicAdd(&cnt[edst[e]], 1);
}

__device__ __forceinline__ void csr_fill_body(
    int blk, const int* __restrict__ edst, const int* __restrict__ esrc,
    const float* __restrict__ edge_vec, int* __restrict__ cursor,
    float* __restrict__ vec_csr, int E) {
    int e = blk * 256 + threadIdx.x;
    if (e < E) {
        int d = edst[e];
        int p = atomicAdd(&cursor[d], 1);
        float4 vv = {edge_vec[e * 3 + 0], edge_vec[e * 3 + 1], edge_vec[e * 3 + 2],
                     __int_as_float(esrc[e])};
        *(float4*)(vec_csr + (size_t)p * 4) = vv;
    }
}

// node fctp: 16 nodes/block; smem: [0,16K) w0 | [16K,32K) w1 | [32K,35K) sh
__device__ __forceinline__ void node_fctp_body(
    int blk, int path,
    const float* __restrict__ s, const float* __restrict__ v,
    const float* __restrict__ attr, const float* __restrict__ Wfp,
    float* __restrict__ sc_s, float* __restrict__ sc_v,
    float* __restrict__ xsv, int N, char* smem) {
    float* w0 = (float*)smem;
    float* w1 = (float*)(smem + 16384);
    float (*sh)[96] = (float(*)[96])(smem + 32768);
    int ln = threadIdx.x >> 5, w = threadIdx.x & 31;
    const float4* W0p = (const float4*)(Wfp + path * 8192);
    const float4* W1p = (const float4*)(Wfp + path * 8192 + 4096);
    for (int i = threadIdx.x; i < 1024; i += 256) {
        ((float4*)w0)[i] = W0p[i];
        ((float4*)w1)[i] = W1p[i];
    }
    for (int g = 0; g < 2; g++) {
        int n = blk * 16 + g * 8 + ln;
        bool valid = n < N;
        __syncthreads();
        if (valid) {
            if (path == 0) {
                sh[ln][w] = s[n * 32 + w];
            } else {
                sh[ln][w * 3 + 0] = v[n * 96 + w * 3 + 0];
                sh[ln][w * 3 + 1] = v[n * 96 + w * 3 + 1];
                sh[ln][w * 3 + 2] = v[n * 96 + w * 3 + 2];
            }
        }
        __syncthreads();
        if (!valid) continue;
        float4 at = *(const float4*)(attr + n * 4);
        if (path == 0) {
            float acc0 = 0.f, acc1 = 0.f;
            for (int u = 0; u < 32; u++) {
                float su = sh[ln][u];
                float4 W0v = *(const float4*)(w0 + u * 128 + w * 4);
                float4 W1v = *(const float4*)(w1 + u * 128 + w * 4);
                float d0 = at.x * W0v.x + at.y * W0v.y + at.z * W0v.z + at.w * W0v.w;
                float d1 = at.x * W1v.x + at.y * W1v.y + at.z * W1v.z + at.w * W1v.w;
                acc0 += su * d0;
                acc1 += su * d1;
            }
            sc_s[n * 32 + w] = acc0 * NORM128_F;
            xsv[(size_t)n * 128 + w * 4 + 3] = acc1 * NORM128_F;
        } else {
            float a00 = 0, a01 = 0, a02 = 0, a10 = 0, a11 = 0, a12 = 0;
            for (int u = 0; u < 32; u++) {
                float vu0 = sh[ln][u * 3 + 0];
                float vu1 = sh[ln][u * 3 + 1];
                float vu2 = sh[ln][u * 3 + 2];
                float4 W0v = *(const float4*)(w0 + u * 128 + w * 4);
                float4 W1v = *(const float4*)(w1 + u * 128 + w * 4);
                float d0 = at.x * W0v.x + at.y * W0v.y + at.z * W0v.z + at.w * W0v.w;
                float d1 = at.x * W1v.x + at.y * W1v.y + at.z * W1v.z + at.w * W1v.w;
                a00 += vu0 * d0; a01 += vu1 * d0; a02 += vu2 * d0;
                a10 += vu0 * d1; a11 += vu1 * d1; a12 += vu2 * d1;
            }
            sc_v[n * 96 + w * 3 + 0] = a00 * NORM128_F;
            sc_v[n * 96 + w * 3 + 1] = a01 * NORM128_F;
            sc_v[n * 96 + w * 3 + 2] = a02 * NORM128_F;
            float* xp = xsv + (size_t)n * 128 + w * 4;
            xp[0] = a10 * NORM128_F;
            xp[1] = a11 * NORM128_F;
            xp[2] = a12 * NORM128_F;
        }
    }
}

// ---------------------------------------------------------------- mega kernels
// tab blocks FIRST so the table generation starts immediately.
__global__ __launch_bounds__(256) void mega1(
    int nTab, int nInit, int nSetup,
    const float* __restrict__ x, float* __restrict__ s, float* __restrict__ v,
    const float* __restrict__ Wfc1, const float* __restrict__ Wfc2,
    const float* __restrict__ Wsc0, const float* __restrict__ Wl10,
    const float* __restrict__ Wsc1, const float* __restrict__ Wl11,
    const float* __restrict__ Wl20, const float* __restrict__ Wl21,
    float* __restrict__ Wfp, unsigned* __restrict__ Wupk,
    unsigned* __restrict__ tab,
    const int* __restrict__ edst, int* __restrict__ cnt, int N, int E) {
    __shared__ float sh_h[4][64];
    int b = blockIdx.x;
    if (b < nTab) { tab_gen_body(b, Wfc1, Wfc2, tab, sh_h); return; }
    b -= nTab;
    if (b < nInit) { init_sv_body(b, x, s, v, N); return; }
    b -= nInit;
    if (b < nSetup) {
        setup_weights_body(b, Wsc0, Wl10, Wsc1, Wl11, Wl20, Wl21, Wfp, Wupk);
        return;
    }
    b -= nSetup;
    csr_count_body(b, edst, cnt, E);
}

__global__ void csr_scan(const int* __restrict__ cnt, int* __restrict__ off,
                         int* __restrict__ cursor, int N) {
    __shared__ int sums[256];
    int t = threadIdx.x;
    int chunk = (N + 255) / 256;
    int lo = t * chunk, hi = lo + chunk; if (hi > N) hi = N;
    int s = 0;
    for (int i = lo; i < hi; i++) s += cnt[i];
    sums[t] = s;
    __syncthreads();
    for (int d = 1; d < 256; d <<= 1) {
        int v = (t >= d) ? sums[t - d] : 0;
        __syncthreads();
        sums[t] += v;
        __syncthreads();
    }
    int run = (t == 0) ? 0 : sums[t - 1];
    for (int i = lo; i < hi; i++) {
        off[i] = run; cursor[i] = run;
        run += cnt[i];
    }
}

// csr_fill || fctp(layer0, both paths)   (no agg zeroing needed: gather+update
// covers every agg element with plain stores held in LDS — agg never hits HBM)
__global__ __launch_bounds__(256, 4) void mega2(
    int nFill, int nF,
    const int* __restrict__ edst, const int* __restrict__ esrc,
    const float* __restrict__ edge_vec, int* __restrict__ cursor,
    float* __restrict__ vec_csr, int E,
    const float* __restrict__ s, const float* __restrict__ v,
    const float* __restrict__ attr, const float* __restrict__ Wfp,
    float* __restrict__ sc_s, float* __restrict__ sc_v,
    float* __restrict__ xsv, int N) {
    __shared__ __align__(16) char smem[35840];
    int b = blockIdx.x;
    if (b < nFill) {
        csr_fill_body(b, edst, esrc, edge_vec, cursor, vec_csr, E);
        return;
    }
    b -= nFill;
    node_fctp_body(b % nF, b / nF, s, v, attr, Wfp, sc_s, sc_v, xsv, N, smem);
}

// next-layer fctp (both paths) as a standalone dispatch
__global__ __launch_bounds__(256, 4) void fctp_only(
    int nF,
    const float* __restrict__ s, const float* __restrict__ v,
    const float* __restrict__ attr, const float* __restrict__ Wfp,
    float* __restrict__ sc_s, float* __restrict__ sc_v,
    float* __restrict__ xsv, int N) {
    __shared__ __align__(16) char smem[35840];
    node_fctp_body(blockIdx.x % nF, blockIdx.x / nF, s, v, attr, Wfp,
                   sc_s, sc_v, xsv, N, smem);
}

// ---------------------------------------------------------------- gather+update
// 2 nodes/block, 128 threads each (4 quarter-waves striding slots by 4).
// Per-edge weights regenerated inline from the w(len) table. The complete agg
// vector stays in LDS (red); the node update (second fctp + s,v update) runs
// in the same block — agg never touches global memory, no atomics anywhere.
__global__ __launch_bounds__(256, 4) void gather_update(
    const int* __restrict__ off, const int* __restrict__ cnt,
    const unsigned* __restrict__ tab,
    const float* __restrict__ vec_csr, const float* __restrict__ xsv,
    const float* __restrict__ attr, const unsigned* __restrict__ Wupk,
    const float* __restrict__ sc_s, const float* __restrict__ sc_v,
    float* __restrict__ s, float* __restrict__ v, int N) {
    __shared__ float red[2][8][32];
    int pair = threadIdx.x >> 7;
    int node = blockIdx.x * 2 + pair;
    int ql = threadIdx.x & 127;
    int quarter = ql >> 5;
    int u = ql & 31;
    bool active = node < N;
    int o = 0, deg = 0;
    if (active) { o = off[node]; deg = cnt[node]; }
    float as0 = 0, as1 = 0;
    float av00 = 0, av01 = 0, av02 = 0, av10 = 0, av11 = 0, av12 = 0;

    auto body = [&](int slot) {
        size_t p = (size_t)slot;
        float4 vv = *(const float4*)(vec_csr + p * 4);
        int src = __float_as_int(vv.w);
        float len = sqrtf(vv.x * vv.x + vv.y * vv.y + vv.z * vv.z);
        float rinv = SQRT3_F / (len + 1e-9f);
        float y0 = vv.x * rinv, y1 = vv.y * rinv, y2 = vv.z * rinv;
        float t = fminf(len, 3.99995f) * 128.0f;
        int ti = (int)t;
        float fr = t - (float)ti;
        const unsigned* tr = tab + ti * 64 + u;
        unsigned qa0 = tr[0],  qa1 = tr[32];
        unsigned qb0 = tr[64], qb1 = tr[96];
        float4 x4 = *(const float4*)(xsv + (size_t)src * 128 + u * 4);
        float wa0 = bf2f((unsigned short)qa0), wb0 = bf2f((unsigned short)qb0);
        float wc0 = bf2f((unsigned short)(qa0 >> 16)), wd0 = bf2f((unsigned short)(qb0 >> 16));
        float wa1 = bf2f((unsigned short)qa1), wb1 = bf2f((unsigned short)qb1);
        float wc1 = bf2f((unsigned short)(qa1 >> 16)), wd1 = bf2f((unsigned short)(qb1 >> 16));
        float wa = wa0 + fr * (wb0 - wa0);   // w0[u]
        float wc = wc0 + fr * (wd0 - wc0);   // w2[u]
        float wb = wa1 + fr * (wb1 - wa1);   // w1[u]
        float wd = wc1 + fr * (wd1 - wc1);   // w3[u]
        as0 += wa * x4.w;
        as1 += wb * (y0 * x4.x + y1 * x4.y + y2 * x4.z) * INV_SQRT3_F;
        float tt = wc * x4.w;
        av00 += tt * y0;  av01 += tt * y1;  av02 += tt * y2;
        av10 += wd * x4.x; av11 += wd * x4.y; av12 += wd * x4.z;
    };

    int i = quarter;
    for (; i + 4 < deg; i += 8) { body(o + i); body(o + i + 4); }
    for (; i < deg; i += 4) body(o + i);

    as0 += __shfl_down(as0, 32);  as1 += __shfl_down(as1, 32);
    av00 += __shfl_down(av00, 32); av01 += __shfl_down(av01, 32); av02 += __shfl_down(av02, 32);
    av10 += __shfl_down(av10, 32); av11 += __shfl_down(av11, 32); av12 += __shfl_down(av12, 32);

    int lane = threadIdx.x & 63;
    int upper_wave = (threadIdx.x >> 6) & 1;
    if (upper_wave && lane < 32) {
        red[pair][0][u] = as0;  red[pair][1][u] = as1;
        red[pair][2][u] = av00; red[pair][3][u] = av01; red[pair][4][u] = av02;
        red[pair][5][u] = av10; red[pair][6][u] = av11; red[pair][7][u] = av12;
    }
    __syncthreads();
    if (!upper_wave && lane < 32) {
        // final scaled agg vector -> red (layout matches update's access below)
        red[pair][0][u] = (as0 + red[pair][0][u]) * INV_SQRTNN_F;   // agg_s[u]
        red[pair][1][u] = (as1 + red[pair][1][u]) * INV_SQRTNN_F;   // agg_s[32+u]
        red[pair][2][u] = (av00 + red[pair][2][u]) * INV_SQRTNN_F;  // agg_v[u][0]
        red[pair][3][u] = (av01 + red[pair][3][u]) * INV_SQRTNN_F;
        red[pair][4][u] = (av02 + red[pair][4][u]) * INV_SQRTNN_F;
        red[pair][5][u] = (av10 + red[pair][5][u]) * INV_SQRTNN_F;  // agg_v[32+u][0]
        red[pair][6][u] = (av11 + red[pair][6][u]) * INV_SQRTNN_F;
        red[pair][7][u] = (av12 + red[pair][7][u]) * INV_SQRTNN_F;
    }
    __syncthreads();

    // ---- update phase: quarter-0 lanes (32 per node) do the second fctp + update
    if (active && quarter == 0) {
        int w = u;
        float4 at = *(const float4*)(attr + node * 4);
        float acc_s = 0.f, a0 = 0.f, a1 = 0.f, a2 = 0.f;
#pragma unroll 8
        for (int uu = 0; uu < 64; uu++) {
            float gs, g0, g1, g2;
            if (uu < 32) {
                gs = red[pair][0][uu];
                g0 = red[pair][2][uu]; g1 = red[pair][3][uu]; g2 = red[pair][4][uu];
            } else {
                gs = red[pair][1][uu - 32];
                g0 = red[pair][5][uu - 32]; g1 = red[pair][6][uu - 32]; g2 = red[pair][7][uu - 32];
            }
            uint4 pv = *(const uint4*)(Wupk + uu * 128 + w * 4);
            float w20x = bf2f((unsigned short)pv.x), w21x = bf2f((unsigned short)(pv.x >> 16));
            float w20y = bf2f((unsigned short)pv.y), w21y = bf2f((unsigned short)(pv.y >> 16));
            float w20z = bf2f((unsigned short)pv.z), w21z = bf2f((unsigned short)(pv.z >> 16));
            float w20w = bf2f((unsigned short)pv.w), w21w = bf2f((unsigned short)(pv.w >> 16));
            float d0 = at.x * w20x + at.y * w20y + at.z * w20z + at.w * w20w;
            float d1 = at.x * w21x + at.y * w21y + at.z * w21z + at.w * w21w;
            acc_s += gs * d0;
            a0 += g0 * d1; a1 += g1 * d1; a2 += g2 * d1;
        }
        float os = acc_s * NORM256_F;
        float sn = C_S_F * sc_s[node * 32 + w] + C_X_F * os;
        float sig = 1.0f / (1.0f + __expf(-sn));
        s[node * 32 + w] += sn * sig;   // silu(sn)
        float ov0 = a0 * NORM256_F, ov1 = a1 * NORM256_F, ov2 = a2 * NORM256_F;
        v[node * 96 + w * 3 + 0] += (C_S_F * sc_v[node * 96 + w * 3 + 0] + C_X_F * ov0) * sig;
        v[node * 96 + w * 3 + 1] += (C_S_F * sc_v[node * 96 + w * 3 + 1] + C_X_F * ov1) * sig;
        v[node * 96 + w * 3 + 2] += (C_S_F * sc_v[node * 96 + w * 3 + 2] + C_X_F * ov2) * sig;
    }
}

// ---------------------------------------------------------------- readout
__global__ __launch_bounds__(256) void readout(
    const float* __restrict__ s, const float* __restrict__ attr,
    const float* __restrict__ Wread, const int* __restrict__ batch,
    float* __restrict__ out, int N, float pool_scale) {
    __shared__ float wr[2048];
    __shared__ float red[NGRAPH * 16];
    for (int i = threadIdx.x; i < 2048; i += 256) wr[i] = Wread[i];
    if (threadIdx.x < NGRAPH * 16) red[threadIdx.x] = 0.f;
    __syncthreads();
    int ln = threadIdx.x >> 4, w = threadIdx.x & 15;
    for (int g = 0; g < 4; g++) {
        int n = blockIdx.x * 64 + g * 16 + ln;
        if (n < N) {
            float4 at = *(const float4*)(attr + n * 4);
            float fa[4] = {at.x, at.y, at.z, at.w};
            float acc = 0.f;
            for (int u = 0; u < 32; u++) {
                float su = s[n * 32 + u];
                int base = u * 64 + w;
#pragma unroll
                for (int a = 0; a < 4; a++) acc += su * fa[a] * wr[base + a * 16];
            }
            atomicAdd(&red[batch[n] * 16 + w], acc);
        }
    }
    __syncthreads();
    if (threadIdx.x < NGRAPH * 16) {
        float val = red[threadIdx.x];
        if (val != 0.f)
            atomicAdd(&out[threadIdx.x], val * NORM128_F * pool_scale);
    }
}

// ---------------------------------------------------------------- launch
extern "C" void kernel_launch(void* const* d_in, const int* in_sizes, int n_in,
                              void* d_out, int out_size, void* d_ws, size_t ws_size,
                              hipStream_t stream) {
    const float* x        = (const float*)d_in[0];
    const float* nattr    = (const float*)d_in[1];
    const float* edge_vec = (const float*)d_in[2];
    const int*   batch    = (const int*)d_in[3];
    const int*   esrc     = (const int*)d_in[4];
    const int*   edst     = (const int*)d_in[5];
    const float* Wsc0  = (const float*)d_in[6];
    const float* Wsc1  = (const float*)d_in[7];
    const float* Wl10  = (const float*)d_in[8];
    const float* Wl11  = (const float*)d_in[9];
    const float* Wfc1  = (const float*)d_in[10];
    const float* Wfc2  = (const float*)d_in[11];
    const float* Wl20  = (const float*)d_in[12];
    const float* Wl21  = (const float*)d_in[13];
    const float* Wread = (const float*)d_in[14];

    int N = in_sizes[0] / (MUL * 4);
    int E = in_sizes[2] / 3;

    float* p = (float*)d_ws;
    float* vec_csr = p; p += (size_t)E * 4;     // {ex,ey,ez,src-bits}
    unsigned* tab = (unsigned*)p; p += 2 * NT * 64;  // w(len) tables, packed bf16
    float* Wfp    = p; p += 32768;              // 2 layers x 4 matrices x 4096
    unsigned* Wupk = (unsigned*)p; p += 16384;  // 2 layers x 8192 packed pair dwords
    float* s_buf  = p; p += (size_t)N * 32;
    float* v_buf  = p; p += (size_t)N * 96;
    float* sc_s   = p; p += (size_t)N * 32;
    float* sc_v   = p; p += (size_t)N * 96;
    float* xsv    = p; p += (size_t)N * 128;    // {xv0,xv1,xv2,xs} per (n,u)
    int* cnt     = (int*)p; p += N;
    int* off     = (int*)p; p += N;
    int* cursor  = (int*)p; p += N;

    hipMemsetAsync(d_out, 0, (size_t)out_size * sizeof(float), stream);
    hipMemsetAsync(cnt, 0, (size_t)N * sizeof(int), stream);

    int nTab   = (2 * NT + 3) / 4;              // 4 rows per block
    int nInit  = (N * 128 + 255) / 256;
    int nSetup = 192;
    int nCount = (E + 255) / 256;
    mega1<<<nTab + nInit + nSetup + nCount, 256, 0, stream>>>(
        nTab, nInit, nSetup, x, s_buf, v_buf,
        Wfc1, Wfc2, Wsc0, Wl10, Wsc1, Wl11, Wl20, Wl21,
        Wfp, Wupk, tab, edst, cnt, N, E);

    csr_scan<<<1, 256, 0, stream>>>(cnt, off, cursor, N);

    int nFill = (E + 255) / 256;
    int nF = (N + 15) / 16;
    mega2<<<nFill + 2 * nF, 256, 0, stream>>>(
        nFill, nF, edst, esrc, edge_vec, cursor, vec_csr, E,
        s_buf, v_buf, nattr, Wfp, sc_s, sc_v, xsv, N);

    int nG = (N + 1) / 2;

    // ---- layer 0: gather+update fused, then next-layer fctp
    gather_update<<<nG, 256, 0, stream>>>(
        off, cnt, tab, vec_csr, xsv, nattr, Wupk,
        sc_s, sc_v, s_buf, v_buf, N);
    fctp_only<<<2 * nF, 256, 0, stream>>>(
        nF, s_buf, v_buf, nattr, Wfp + 16384, sc_s, sc_v, xsv, N);

    // ---- layer 1: gather+update fused (no further fctp)
    gather_update<<<nG, 256, 0, stream>>>(
        off, cnt, tab + NT * 64, vec_csr, xsv, nattr, Wupk + 8192,
        sc_s, sc_v, s_buf, v_buf, N);

    float pool_scale = (float)(1.0 / sqrt((double)N / (double)NGRAPH));
    readout<<<(N + 63) / 64, 256, 0, stream>>>(
        s_buf, nattr, Wread, batch, (float*)d_out, N, pool_scale);
}

// Round 12
// 289.344 us; speedup vs baseline: 1.0654x; 1.0654x over previous
//
#include <hip/hip_runtime.h>
#include <math.h>

#define MUL 32
#define NATTR 4
#define NBASIS 10
#define HID 64
#define OUT_DIM 16
#define NGRAPH 8
#define NT 513      // w(len) table entries: len = i/128, i in [0,512]

#define PI_F 3.14159265358979323846f
#define SQRT3_F 1.7320508075688772f
#define INV_SQRT3_F 0.5773502691896258f
#define INV_SQRT10_F 0.31622776601683794f
#define INV_SQRTNN_F 0.17677669529663687f   // 1/sqrt(32)
#define NORM128_F 0.08838834764831845f      // 1/sqrt(128)
#define NORM256_F 0.0625f                   // 1/sqrt(256)
#define C_S_F 0.3826834323650898f           // sin(pi/8)
#define C_X_F 0.9238795325112867f           // cos(pi/8)
#define CSTEP_F (4.0f/9.0f)                 // linspace(0,4,10) step

__device__ inline unsigned short f2bf(float x) {
    unsigned u = __float_as_uint(x);
    u += 0x7FFF + ((u >> 16) & 1);          // round-to-nearest-even
    return (unsigned short)(u >> 16);
}
__device__ inline float bf2f(unsigned short h) {
    return __uint_as_float(((unsigned)h) << 16);
}

// ---------------------------------------------------------------- bodies
__device__ __forceinline__ void init_sv_body(
    int blk, const float* __restrict__ x,
    float* __restrict__ s, float* __restrict__ v, int N) {
    int i = blk * 256 + threadIdx.x;
    if (i >= N * 128) return;
    int n = i >> 7, c = i & 127;
    float val = x[i];
    if (c < 32) s[n * 32 + c] = val;
    else        v[n * 96 + (c - 32)] = val;
}

__device__ __forceinline__ void setup_weights_body(
    int blk,
    const float* __restrict__ Wsc0, const float* __restrict__ Wl10,
    const float* __restrict__ Wsc1, const float* __restrict__ Wl11,
    const float* __restrict__ Wl20, const float* __restrict__ Wl21,
    float* __restrict__ Wfp, unsigned* __restrict__ Wupk) {
    int i = blk * 256 + threadIdx.x;
    if (i < 32768) {
        int idx = i >> 12;          // l*4 + m
        int r = i & 4095;
        int l = idx >> 2, m = idx & 3;
        const float* base = (m == 0 ? Wsc0 : m == 1 ? Wl10 : m == 2 ? Wsc1 : Wl11)
                            + l * 4096;
        int u = r >> 7, rr = r & 127, a = rr >> 5, ww = rr & 31;
        Wfp[idx * 4096 + u * 128 + ww * 4 + a] = base[r];
    } else if (i < 49152) {
        int j = i - 32768;
        int l = j >> 13;
        int r = j & 8191;
        int u = r >> 7, rr = r & 127, a = rr >> 5, ww = rr & 31;
        unsigned lo = f2bf(Wl20[l * 8192 + r]);
        unsigned hi = f2bf(Wl21[l * 8192 + r]);
        Wupk[l * 8192 + u * 128 + ww * 4 + a] = lo | (hi << 16);
    }
}

// w(len) table generator, cooperative: one 64-thread group per table row.
__device__ __forceinline__ void tab_gen_body(
    int blk, const float* __restrict__ Wfc1, const float* __restrict__ Wfc2,
    unsigned* __restrict__ tab, float (*sh_h)[64]) {
    int g = threadIdx.x >> 6;       // row group 0..3
    int n = threadIdx.x & 63;       // h index / output j
    int row = blk * 4 + g;
    bool valid = row < 2 * NT;
    int l = valid ? row / NT : 0;
    int i = valid ? row % NT : 0;
    float len = (float)i * (1.0f / 128.0f);
    float uu = len * 0.5f - 2.0f;
    float cut = (uu > 0.0f) ? 0.0f
              : ((uu < -1.0f) ? 1.0f : 0.5f * (1.0f - __cosf(PI_F * uu)));
    const float* W1 = Wfc1 + l * 640;
    float a = 0.f;
#pragma unroll
    for (int k = 0; k < 10; k++) {
        float d = (len - k * CSTEP_F) * 2.5f;
        float e = __expf(-d * d) * cut;
        a += e * W1[k * 64 + n];
    }
    a *= INV_SQRT10_F;
    sh_h[g][n] = a / (1.0f + __expf(-a));
    __syncthreads();
    if (!valid) return;
    const float* W2 = Wfc2 + l * 8192;
    float w0 = 0.f, w1 = 0.f;
#pragma unroll 8
    for (int nn = 0; nn < 64; nn++) {
        float hn = sh_h[g][nn];
        w0 += hn * W2[nn * 128 + n];
        w1 += hn * W2[nn * 128 + 64 + n];
    }
    w0 *= 0.125f; w1 *= 0.125f;
    tab[(size_t)l * NT * 64 + i * 64 + n] =
        (unsigned)f2bf(w0) | ((unsigned)f2bf(w1) << 16);
}

__device__ __forceinline__ void csr_count_body(
    int blk, const int* __restrict__ edst, int* __restrict__ cnt, int E) {
    int e = blk * 256 + threadIdx.x;
    if (e < E) atomicAdd(&cnt[edst[e]], 1);
}

__device__ __forceinline__ void csr_fill_body(
    int blk, const int* __restrict__ edst, const int* __restrict__ esrc,
    const float* __restrict__ edge_vec, int* __restrict__ cursor,
    float* __restrict__ vec_csr, int E) {
    int e = blk * 256 + threadIdx.x;
    if (e < E) {
        int d = edst[e];
        int p = atomicAdd(&cursor[d], 1);
        float4 vv = {edge_vec[e * 3 + 0], edge_vec[e * 3 + 1], edge_vec[e * 3 + 2],
                     __int_as_float(esrc[e])};
        *(float4*)(vec_csr + (size_t)p * 4) = vv;
    }
}

// node fctp: 16 nodes/block; smem: [0,16K) w0 | [16K,32K) w1 | [32K,35K) sh
__device__ __forceinline__ void node_fctp_body(
    int blk, int path,
    const float* __restrict__ s, const float* __restrict__ v,
    const float* __restrict__ attr, const float* __restrict__ Wfp,
    float* __restrict__ sc_s, float* __restrict__ sc_v,
    float* __restrict__ xsv, int N, char* smem) {
    float* w0 = (float*)smem;
    float* w1 = (float*)(smem + 16384);
    float (*sh)[96] = (float(*)[96])(smem + 32768);
    int ln = threadIdx.x >> 5, w = threadIdx.x & 31;
    const float4* W0p = (const float4*)(Wfp + path * 8192);
    const float4* W1p = (const float4*)(Wfp + path * 8192 + 4096);
    for (int i = threadIdx.x; i < 1024; i += 256) {
        ((float4*)w0)[i] = W0p[i];
        ((float4*)w1)[i] = W1p[i];
    }
    for (int g = 0; g < 2; g++) {
        int n = blk * 16 + g * 8 + ln;
        bool valid = n < N;
        __syncthreads();
        if (valid) {
            if (path == 0) {
                sh[ln][w] = s[n * 32 + w];
            } else {
                sh[ln][w * 3 + 0] = v[n * 96 + w * 3 + 0];
                sh[ln][w * 3 + 1] = v[n * 96 + w * 3 + 1];
                sh[ln][w * 3 + 2] = v[n * 96 + w * 3 + 2];
            }
        }
        __syncthreads();
        if (!valid) continue;
        float4 at = *(const float4*)(attr + n * 4);
        if (path == 0) {
            float acc0 = 0.f, acc1 = 0.f;
            for (int u = 0; u < 32; u++) {
                float su = sh[ln][u];
                float4 W0v = *(const float4*)(w0 + u * 128 + w * 4);
                float4 W1v = *(const float4*)(w1 + u * 128 + w * 4);
                float d0 = at.x * W0v.x + at.y * W0v.y + at.z * W0v.z + at.w * W0v.w;
                float d1 = at.x * W1v.x + at.y * W1v.y + at.z * W1v.z + at.w * W1v.w;
                acc0 += su * d0;
                acc1 += su * d1;
            }
            sc_s[n * 32 + w] = acc0 * NORM128_F;
            xsv[(size_t)n * 128 + w * 4 + 3] = acc1 * NORM128_F;
        } else {
            float a00 = 0, a01 = 0, a02 = 0, a10 = 0, a11 = 0, a12 = 0;
            for (int u = 0; u < 32; u++) {
                float vu0 = sh[ln][u * 3 + 0];
                float vu1 = sh[ln][u * 3 + 1];
                float vu2 = sh[ln][u * 3 + 2];
                float4 W0v = *(const float4*)(w0 + u * 128 + w * 4);
                float4 W1v = *(const float4*)(w1 + u * 128 + w * 4);
                float d0 = at.x * W0v.x + at.y * W0v.y + at.z * W0v.z + at.w * W0v.w;
                float d1 = at.x * W1v.x + at.y * W1v.y + at.z * W1v.z + at.w * W1v.w;
                a00 += vu0 * d0; a01 += vu1 * d0; a02 += vu2 * d0;
                a10 += vu0 * d1; a11 += vu1 * d1; a12 += vu2 * d1;
            }
            sc_v[n * 96 + w * 3 + 0] = a00 * NORM128_F;
            sc_v[n * 96 + w * 3 + 1] = a01 * NORM128_F;
            sc_v[n * 96 + w * 3 + 2] = a02 * NORM128_F;
            float* xp = xsv + (size_t)n * 128 + w * 4;
            xp[0] = a10 * NORM128_F;
            xp[1] = a11 * NORM128_F;
            xp[2] = a12 * NORM128_F;
        }
    }
}

// ---------------------------------------------------------------- mega kernels
// tab blocks FIRST so the table generation starts immediately.
__global__ __launch_bounds__(256) void mega1(
    int nTab, int nInit, int nSetup,
    const float* __restrict__ x, float* __restrict__ s, float* __restrict__ v,
    const float* __restrict__ Wfc1, const float* __restrict__ Wfc2,
    const float* __restrict__ Wsc0, const float* __restrict__ Wl10,
    const float* __restrict__ Wsc1, const float* __restrict__ Wl11,
    const float* __restrict__ Wl20, const float* __restrict__ Wl21,
    float* __restrict__ Wfp, unsigned* __restrict__ Wupk,
    unsigned* __restrict__ tab,
    const int* __restrict__ edst, int* __restrict__ cnt, int N, int E) {
    __shared__ float sh_h[4][64];
    int b = blockIdx.x;
    if (b < nTab) { tab_gen_body(b, Wfc1, Wfc2, tab, sh_h); return; }
    b -= nTab;
    if (b < nInit) { init_sv_body(b, x, s, v, N); return; }
    b -= nInit;
    if (b < nSetup) {
        setup_weights_body(b, Wsc0, Wl10, Wsc1, Wl11, Wl20, Wl21, Wfp, Wupk);
        return;
    }
    b -= nSetup;
    csr_count_body(b, edst, cnt, E);
}

__global__ void csr_scan(const int* __restrict__ cnt, int* __restrict__ off,
                         int* __restrict__ cursor, int N) {
    __shared__ int sums[256];
    int t = threadIdx.x;
    int chunk = (N + 255) / 256;
    int lo = t * chunk, hi = lo + chunk; if (hi > N) hi = N;
    int s = 0;
    for (int i = lo; i < hi; i++) s += cnt[i];
    sums[t] = s;
    __syncthreads();
    for (int d = 1; d < 256; d <<= 1) {
        int v = (t >= d) ? sums[t - d] : 0;
        __syncthreads();
        sums[t] += v;
        __syncthreads();
    }
    int run = (t == 0) ? 0 : sums[t - 1];
    for (int i = lo; i < hi; i++) {
        off[i] = run; cursor[i] = run;
        run += cnt[i];
    }
}

// csr_fill || fctp(layer0, both paths)
__global__ __launch_bounds__(256, 4) void mega2(
    int nFill, int nF,
    const int* __restrict__ edst, const int* __restrict__ esrc,
    const float* __restrict__ edge_vec, int* __restrict__ cursor,
    float* __restrict__ vec_csr, int E,
    const float* __restrict__ s, const float* __restrict__ v,
    const float* __restrict__ attr, const float* __restrict__ Wfp,
    float* __restrict__ sc_s, float* __restrict__ sc_v,
    float* __restrict__ xsv, int N) {
    __shared__ __align__(16) char smem[35840];
    int b = blockIdx.x;
    if (b < nFill) {
        csr_fill_body(b, edst, esrc, edge_vec, cursor, vec_csr, E);
        return;
    }
    b -= nFill;
    node_fctp_body(b % nF, b / nF, s, v, attr, Wfp, sc_s, sc_v, xsv, N, smem);
}

// next-layer fctp (both paths) as a standalone dispatch
__global__ __launch_bounds__(256, 4) void fctp_only(
    int nF,
    const float* __restrict__ s, const float* __restrict__ v,
    const float* __restrict__ attr, const float* __restrict__ Wfp,
    float* __restrict__ sc_s, float* __restrict__ sc_v,
    float* __restrict__ xsv, int N) {
    __shared__ __align__(16) char smem[35840];
    node_fctp_body(blockIdx.x % nF, blockIdx.x / nF, s, v, attr, Wfp,
                   sc_s, sc_v, xsv, N, smem);
}

// ---------------------------------------------------------------- gather+update
// 2 nodes/block, 128 threads each (4 quarter-waves striding slots by 4).
// Per-edge weights regenerated inline from the w(len) table. The complete agg
// vector stays in LDS (red); the node update runs in the same block with ALL
// 128 threads (quarter q covers uu in [q*16,(q+1)*16), shfl+LDS reduction) —
// agg never touches global memory, no atomics anywhere.
__global__ __launch_bounds__(256, 4) void gather_update(
    const int* __restrict__ off, const int* __restrict__ cnt,
    const unsigned* __restrict__ tab,
    const float* __restrict__ vec_csr, const float* __restrict__ xsv,
    const float* __restrict__ attr, const unsigned* __restrict__ Wupk,
    const float* __restrict__ sc_s, const float* __restrict__ sc_v,
    float* __restrict__ s, float* __restrict__ v, int N) {
    __shared__ float red[2][8][32];
    __shared__ float part[2][4][32];
    int pair = threadIdx.x >> 7;
    int node = blockIdx.x * 2 + pair;
    int ql = threadIdx.x & 127;
    int quarter = ql >> 5;
    int u = ql & 31;
    bool active = node < N;
    int o = 0, deg = 0;
    if (active) { o = off[node]; deg = cnt[node]; }
    float as0 = 0, as1 = 0;
    float av00 = 0, av01 = 0, av02 = 0, av10 = 0, av11 = 0, av12 = 0;

    auto body = [&](int slot) {
        size_t p = (size_t)slot;
        float4 vv = *(const float4*)(vec_csr + p * 4);
        int src = __float_as_int(vv.w);
        float len = sqrtf(vv.x * vv.x + vv.y * vv.y + vv.z * vv.z);
        float rinv = SQRT3_F / (len + 1e-9f);
        float y0 = vv.x * rinv, y1 = vv.y * rinv, y2 = vv.z * rinv;
        float t = fminf(len, 3.99995f) * 128.0f;
        int ti = (int)t;
        float fr = t - (float)ti;
        const unsigned* tr = tab + ti * 64 + u;
        unsigned qa0 = tr[0],  qa1 = tr[32];
        unsigned qb0 = tr[64], qb1 = tr[96];
        float4 x4 = *(const float4*)(xsv + (size_t)src * 128 + u * 4);
        float wa0 = bf2f((unsigned short)qa0), wb0 = bf2f((unsigned short)qb0);
        float wc0 = bf2f((unsigned short)(qa0 >> 16)), wd0 = bf2f((unsigned short)(qb0 >> 16));
        float wa1 = bf2f((unsigned short)qa1), wb1 = bf2f((unsigned short)qb1);
        float wc1 = bf2f((unsigned short)(qa1 >> 16)), wd1 = bf2f((unsigned short)(qb1 >> 16));
        float wa = wa0 + fr * (wb0 - wa0);   // w0[u]
        float wc = wc0 + fr * (wd0 - wc0);   // w2[u]
        float wb = wa1 + fr * (wb1 - wa1);   // w1[u]
        float wd = wc1 + fr * (wd1 - wc1);   // w3[u]
        as0 += wa * x4.w;
        as1 += wb * (y0 * x4.x + y1 * x4.y + y2 * x4.z) * INV_SQRT3_F;
        float tt = wc * x4.w;
        av00 += tt * y0;  av01 += tt * y1;  av02 += tt * y2;
        av10 += wd * x4.x; av11 += wd * x4.y; av12 += wd * x4.z;
    };

    int i = quarter;
    for (; i + 4 < deg; i += 8) { body(o + i); body(o + i + 4); }
    for (; i < deg; i += 4) body(o + i);

    as0 += __shfl_down(as0, 32);  as1 += __shfl_down(as1, 32);
    av00 += __shfl_down(av00, 32); av01 += __shfl_down(av01, 32); av02 += __shfl_down(av02, 32);
    av10 += __shfl_down(av10, 32); av11 += __shfl_down(av11, 32); av12 += __shfl_down(av12, 32);

    int lane = threadIdx.x & 63;
    int upper_wave = (threadIdx.x >> 6) & 1;
    if (upper_wave && lane < 32) {
        red[pair][0][u] = as0;  red[pair][1][u] = as1;
        red[pair][2][u] = av00; red[pair][3][u] = av01; red[pair][4][u] = av02;
        red[pair][5][u] = av10; red[pair][6][u] = av11; red[pair][7][u] = av12;
    }
    __syncthreads();
    if (!upper_wave && lane < 32) {
        // final scaled agg vector -> red
        red[pair][0][u] = (as0 + red[pair][0][u]) * INV_SQRTNN_F;   // agg_s[u]
        red[pair][1][u] = (as1 + red[pair][1][u]) * INV_SQRTNN_F;   // agg_s[32+u]
        red[pair][2][u] = (av00 + red[pair][2][u]) * INV_SQRTNN_F;  // agg_v[u][.]
        red[pair][3][u] = (av01 + red[pair][3][u]) * INV_SQRTNN_F;
        red[pair][4][u] = (av02 + red[pair][4][u]) * INV_SQRTNN_F;
        red[pair][5][u] = (av10 + red[pair][5][u]) * INV_SQRTNN_F;  // agg_v[32+u][.]
        red[pair][6][u] = (av11 + red[pair][6][u]) * INV_SQRTNN_F;
        red[pair][7][u] = (av12 + red[pair][7][u]) * INV_SQRTNN_F;
    }
    __syncthreads();

    // ---- update phase: all 128 threads/node; quarter q covers uu in
    // [q*16,(q+1)*16); shfl+LDS reduce the 4 partials; lower-wave finalizes.
    {
        int half = quarter >> 1;            // uu<32 for q0,q1; uu>=32 for q2,q3
        int ub = (quarter & 1) * 16;        // within-half base
        int w = u;
        float4 at = {0.f, 0.f, 0.f, 0.f};
        if (active) at = *(const float4*)(attr + node * 4);
        const float* rs = red[pair][half];
        const float* r0 = red[pair][2 + 3 * half];
        const float* r1 = red[pair][3 + 3 * half];
        const float* r2 = red[pair][4 + 3 * half];
        float pacc = 0.f, pa0 = 0.f, pa1 = 0.f, pa2 = 0.f;
#pragma unroll
        for (int k = 0; k < 16; k++) {
            int j = ub + k;                 // index within half, 0..31
            float gs = rs[j], g0 = r0[j], g1 = r1[j], g2 = r2[j];
            uint4 pv = *(const uint4*)(Wupk + (half * 32 + j) * 128 + w * 4);
            float w20x = bf2f((unsigned short)pv.x), w21x = bf2f((unsigned short)(pv.x >> 16));
            float w20y = bf2f((unsigned short)pv.y), w21y = bf2f((unsigned short)(pv.y >> 16));
            float w20z = bf2f((unsigned short)pv.z), w21z = bf2f((unsigned short)(pv.z >> 16));
            float w20w = bf2f((unsigned short)pv.w), w21w = bf2f((unsigned short)(pv.w >> 16));
            float d0 = at.x * w20x + at.y * w20y + at.z * w20z + at.w * w20w;
            float d1 = at.x * w21x + at.y * w21y + at.z * w21z + at.w * w21w;
            pacc += gs * d0;
            pa0 += g0 * d1; pa1 += g1 * d1; pa2 += g2 * d1;
        }
        pacc += __shfl_down(pacc, 32);
        pa0 += __shfl_down(pa0, 32);
        pa1 += __shfl_down(pa1, 32);
        pa2 += __shfl_down(pa2, 32);
        if (upper_wave && lane < 32) {
            part[pair][0][u] = pacc;
            part[pair][1][u] = pa0;
            part[pair][2][u] = pa1;
            part[pair][3][u] = pa2;
        }
        __syncthreads();
        if (active && !upper_wave && lane < 32) {
            pacc += part[pair][0][u];
            pa0 += part[pair][1][u];
            pa1 += part[pair][2][u];
            pa2 += part[pair][3][u];
            float os = pacc * NORM256_F;
            float sn = C_S_F * sc_s[node * 32 + w] + C_X_F * os;
            float sig = 1.0f / (1.0f + __expf(-sn));
            s[node * 32 + w] += sn * sig;   // silu(sn)
            float ov0 = pa0 * NORM256_F, ov1 = pa1 * NORM256_F, ov2 = pa2 * NORM256_F;
            v[node * 96 + w * 3 + 0] += (C_S_F * sc_v[node * 96 + w * 3 + 0] + C_X_F * ov0) * sig;
            v[node * 96 + w * 3 + 1] += (C_S_F * sc_v[node * 96 + w * 3 + 1] + C_X_F * ov1) * sig;
            v[node * 96 + w * 3 + 2] += (C_S_F * sc_v[node * 96 + w * 3 + 2] + C_X_F * ov2) * sig;
        }
    }
}

// ---------------------------------------------------------------- readout
__global__ __launch_bounds__(256) void readout(
    const float* __restrict__ s, const float* __restrict__ attr,
    const float* __restrict__ Wread, const int* __restrict__ batch,
    float* __restrict__ out, int N, float pool_scale) {
    __shared__ float wr[2048];
    __shared__ float red[NGRAPH * 16];
    for (int i = threadIdx.x; i < 2048; i += 256) wr[i] = Wread[i];
    if (threadIdx.x < NGRAPH * 16) red[threadIdx.x] = 0.f;
    __syncthreads();
    int ln = threadIdx.x >> 4, w = threadIdx.x & 15;
    for (int g = 0; g < 4; g++) {
        int n = blockIdx.x * 64 + g * 16 + ln;
        if (n < N) {
            float4 at = *(const float4*)(attr + n * 4);
            float fa[4] = {at.x, at.y, at.z, at.w};
            float acc = 0.f;
            for (int u = 0; u < 32; u++) {
                float su = s[n * 32 + u];
                int base = u * 64 + w;
#pragma unroll
                for (int a = 0; a < 4; a++) acc += su * fa[a] * wr[base + a * 16];
            }
            atomicAdd(&red[batch[n] * 16 + w], acc);
        }
    }
    __syncthreads();
    if (threadIdx.x < NGRAPH * 16) {
        float val = red[threadIdx.x];
        if (val != 0.f)
            atomicAdd(&out[threadIdx.x], val * NORM128_F * pool_scale);
    }
}

// ---------------------------------------------------------------- launch
extern "C" void kernel_launch(void* const* d_in, const int* in_sizes, int n_in,
                              void* d_out, int out_size, void* d_ws, size_t ws_size,
                              hipStream_t stream) {
    const float* x        = (const float*)d_in[0];
    const float* nattr    = (const float*)d_in[1];
    const float* edge_vec = (const float*)d_in[2];
    const int*   batch    = (const int*)d_in[3];
    const int*   esrc     = (const int*)d_in[4];
    const int*   edst     = (const int*)d_in[5];
    const float* Wsc0  = (const float*)d_in[6];
    const float* Wsc1  = (const float*)d_in[7];
    const float* Wl10  = (const float*)d_in[8];
    const float* Wl11  = (const float*)d_in[9];
    const float* Wfc1  = (const float*)d_in[10];
    const float* Wfc2  = (const float*)d_in[11];
    const float* Wl20  = (const float*)d_in[12];
    const float* Wl21  = (const float*)d_in[13];
    const float* Wread = (const float*)d_in[14];

    int N = in_sizes[0] / (MUL * 4);
    int E = in_sizes[2] / 3;

    float* p = (float*)d_ws;
    float* vec_csr = p; p += (size_t)E * 4;     // {ex,ey,ez,src-bits}
    unsigned* tab = (unsigned*)p; p += 2 * NT * 64;  // w(len) tables, packed bf16
    float* Wfp    = p; p += 32768;              // 2 layers x 4 matrices x 4096
    unsigned* Wupk = (unsigned*)p; p += 16384;  // 2 layers x 8192 packed pair dwords
    float* s_buf  = p; p += (size_t)N * 32;
    float* v_buf  = p; p += (size_t)N * 96;
    float* sc_s   = p; p += (size_t)N * 32;
    float* sc_v   = p; p += (size_t)N * 96;
    float* xsv    = p; p += (size_t)N * 128;    // {xv0,xv1,xv2,xs} per (n,u)
    int* cnt     = (int*)p; p += N;
    int* off     = (int*)p; p += N;
    int* cursor  = (int*)p; p += N;

    hipMemsetAsync(d_out, 0, (size_t)out_size * sizeof(float), stream);
    hipMemsetAsync(cnt, 0, (size_t)N * sizeof(int), stream);

    int nTab   = (2 * NT + 3) / 4;              // 4 rows per block
    int nInit  = (N * 128 + 255) / 256;
    int nSetup = 192;
    int nCount = (E + 255) / 256;
    mega1<<<nTab + nInit + nSetup + nCount, 256, 0, stream>>>(
        nTab, nInit, nSetup, x, s_buf, v_buf,
        Wfc1, Wfc2, Wsc0, Wl10, Wsc1, Wl11, Wl20, Wl21,
        Wfp, Wupk, tab, edst, cnt, N, E);

    csr_scan<<<1, 256, 0, stream>>>(cnt, off, cursor, N);

    int nFill = (E + 255) / 256;
    int nF = (N + 15) / 16;
    mega2<<<nFill + 2 * nF, 256, 0, stream>>>(
        nFill, nF, edst, esrc, edge_vec, cursor, vec_csr, E,
        s_buf, v_buf, nattr, Wfp, sc_s, sc_v, xsv, N);

    int nG = (N + 1) / 2;

    // ---- layer 0: gather+update fused, then next-layer fctp
    gather_update<<<nG, 256, 0, stream>>>(
        off, cnt, tab, vec_csr, xsv, nattr, Wupk,
        sc_s, sc_v, s_buf, v_buf, N);
    fctp_only<<<2 * nF, 256, 0, stream>>>(
        nF, s_buf, v_buf, nattr, Wfp + 16384, sc_s, sc_v, xsv, N);

    // ---- layer 1: gather+update fused (no further fctp)
    gather_update<<<nG, 256, 0, stream>>>(
        off, cnt, tab + NT * 64, vec_csr, xsv, nattr, Wupk + 8192,
        sc_s, sc_v, s_buf, v_buf, N);

    float pool_scale = (float)(1.0 / sqrt((double)N / (double)NGRAPH));
    readout<<<(N + 63) / 64, 256, 0, stream>>>(
        s_buf, nattr, Wread, batch, (float*)d_out, N, pool_scale);
}

// Round 14
// 276.395 us; speedup vs baseline: 1.1153x; 1.0468x over previous
//
#include <hip/hip_runtime.h>
#include <math.h>

#define MUL 32
#define NATTR 4
#define NBASIS 10
#define HID 64
#define OUT_DIM 16
#define NGRAPH 8
#define NT 513      // w(len) table entries: len = i/128, i in [0,512]

#define PI_F 3.14159265358979323846f
#define SQRT3_F 1.7320508075688772f
#define INV_SQRT3_F 0.5773502691896258f
#define INV_SQRT10_F 0.31622776601683794f
#define INV_SQRTNN_F 0.17677669529663687f   // 1/sqrt(32)
#define NORM128_F 0.08838834764831845f      // 1/sqrt(128)
#define NORM256_F 0.0625f                   // 1/sqrt(256)
#define C_S_F 0.3826834323650898f           // sin(pi/8)
#define C_X_F 0.9238795325112867f           // cos(pi/8)
#define CSTEP_F (4.0f/9.0f)                 // linspace(0,4,10) step

__device__ inline unsigned short f2bf(float x) {
    unsigned u = __float_as_uint(x);
    u += 0x7FFF + ((u >> 16) & 1);          // round-to-nearest-even
    return (unsigned short)(u >> 16);
}
__device__ inline float bf2f(unsigned short h) {
    return __uint_as_float(((unsigned)h) << 16);
}

// ---------------------------------------------------------------- bodies
__device__ __forceinline__ void init_sv_body(
    int blk, const float* __restrict__ x,
    float* __restrict__ s, float* __restrict__ v, int N) {
    int i = blk * 256 + threadIdx.x;
    if (i >= N * 128) return;
    int n = i >> 7, c = i & 127;
    float val = x[i];
    if (c < 32) s[n * 32 + c] = val;
    else        v[n * 96 + (c - 32)] = val;
}

__device__ __forceinline__ void setup_weights_body(
    int blk,
    const float* __restrict__ Wsc0, const float* __restrict__ Wl10,
    const float* __restrict__ Wsc1, const float* __restrict__ Wl11,
    const float* __restrict__ Wl20, const float* __restrict__ Wl21,
    float* __restrict__ Wfp, unsigned* __restrict__ Wupk) {
    int i = blk * 256 + threadIdx.x;
    if (i < 32768) {
        int idx = i >> 12;          // l*4 + m
        int r = i & 4095;
        int l = idx >> 2, m = idx & 3;
        const float* base = (m == 0 ? Wsc0 : m == 1 ? Wl10 : m == 2 ? Wsc1 : Wl11)
                            + l * 4096;
        int u = r >> 7, rr = r & 127, a = rr >> 5, ww = rr & 31;
        Wfp[idx * 4096 + u * 128 + ww * 4 + a] = base[r];
    } else if (i < 49152) {
        int j = i - 32768;
        int l = j >> 13;
        int r = j & 8191;
        int u = r >> 7, rr = r & 127, a = rr >> 5, ww = rr & 31;
        unsigned lo = f2bf(Wl20[l * 8192 + r]);
        unsigned hi = f2bf(Wl21[l * 8192 + r]);
        Wupk[l * 8192 + u * 128 + ww * 4 + a] = lo | (hi << 16);
    }
}

// w(len) table generator, cooperative: one 64-thread group per table row.
__device__ __forceinline__ void tab_gen_body(
    int blk, const float* __restrict__ Wfc1, const float* __restrict__ Wfc2,
    unsigned* __restrict__ tab, float (*sh_h)[64]) {
    int g = threadIdx.x >> 6;       // row group 0..3
    int n = threadIdx.x & 63;       // h index / output j
    int row = blk * 4 + g;
    bool valid = row < 2 * NT;
    int l = valid ? row / NT : 0;
    int i = valid ? row % NT : 0;
    float len = (float)i * (1.0f / 128.0f);
    float uu = len * 0.5f - 2.0f;
    float cut = (uu > 0.0f) ? 0.0f
              : ((uu < -1.0f) ? 1.0f : 0.5f * (1.0f - __cosf(PI_F * uu)));
    const float* W1 = Wfc1 + l * 640;
    float a = 0.f;
#pragma unroll
    for (int k = 0; k < 10; k++) {
        float d = (len - k * CSTEP_F) * 2.5f;
        float e = __expf(-d * d) * cut;
        a += e * W1[k * 64 + n];
    }
    a *= INV_SQRT10_F;
    sh_h[g][n] = a / (1.0f + __expf(-a));
    __syncthreads();
    if (!valid) return;
    const float* W2 = Wfc2 + l * 8192;
    float w0 = 0.f, w1 = 0.f;
#pragma unroll 8
    for (int nn = 0; nn < 64; nn++) {
        float hn = sh_h[g][nn];
        w0 += hn * W2[nn * 128 + n];
        w1 += hn * W2[nn * 128 + 64 + n];
    }
    w0 *= 0.125f; w1 *= 0.125f;
    tab[(size_t)l * NT * 64 + i * 64 + n] =
        (unsigned)f2bf(w0) | ((unsigned)f2bf(w1) << 16);
}

// tab4 converter: tab4[l][ti][u] (uint4, ti in [0,512), u in [0,32)) =
// { tab[ti][u], tab[ti][u+32], pk(delta lo/hi of col u), pk(delta of u+32) }
__device__ __forceinline__ void tab4_body(
    int blk, const unsigned* __restrict__ tab, unsigned* __restrict__ tab4) {
    int id = blk * 256 + threadIdx.x;
    if (id >= 2 * 512 * 32) return;
    int l = id >> 14;
    int r = id & 16383;
    int ti = r >> 5, u = r & 31;
    const unsigned* tb = tab + (size_t)l * NT * 64 + ti * 64;
    unsigned a0 = tb[u],      a1 = tb[u + 32];
    unsigned b0 = tb[64 + u], b1 = tb[64 + u + 32];
    float d0l = bf2f((unsigned short)b0) - bf2f((unsigned short)a0);
    float d0h = bf2f((unsigned short)(b0 >> 16)) - bf2f((unsigned short)(a0 >> 16));
    float d1l = bf2f((unsigned short)b1) - bf2f((unsigned short)a1);
    float d1h = bf2f((unsigned short)(b1 >> 16)) - bf2f((unsigned short)(a1 >> 16));
    uint4 q;
    q.x = a0;
    q.y = a1;
    q.z = (unsigned)f2bf(d0l) | ((unsigned)f2bf(d0h) << 16);
    q.w = (unsigned)f2bf(d1l) | ((unsigned)f2bf(d1h) << 16);
    ((uint4*)tab4)[((size_t)l * 512 + ti) * 32 + u] = q;
}

__device__ __forceinline__ void csr_count_body(
    int blk, const int* __restrict__ edst, int* __restrict__ cnt, int E) {
    int e = blk * 256 + threadIdx.x;
    if (e < E) atomicAdd(&cnt[edst[e]], 1);
}

// csr_fill: pre-normalize y (= sqrt3 * unit) and precompute {ti, fr} per slot.
__device__ __forceinline__ void csr_fill_body(
    int blk, const int* __restrict__ edst, const int* __restrict__ esrc,
    const float* __restrict__ edge_vec, int* __restrict__ cursor,
    float* __restrict__ vec_csr, unsigned* __restrict__ tifr, int E) {
    int e = blk * 256 + threadIdx.x;
    if (e < E) {
        int d = edst[e];
        int p = atomicAdd(&cursor[d], 1);
        float ex = edge_vec[e * 3 + 0], ey = edge_vec[e * 3 + 1], ez = edge_vec[e * 3 + 2];
        float len = sqrtf(ex * ex + ey * ey + ez * ez);
        float rinv = SQRT3_F / (len + 1e-9f);
        float t = fminf(len, 3.99995f) * 128.0f;
        int ti = (int)t;
        float fr = t - (float)ti;
        float4 vv = {ex * rinv, ey * rinv, ez * rinv, __int_as_float(esrc[e])};
        *(float4*)(vec_csr + (size_t)p * 4) = vv;
        uint2 tf = {(unsigned)ti, __float_as_uint(fr)};
        *(uint2*)(tifr + (size_t)p * 2) = tf;
    }
}

// node fctp: 16 nodes/block; smem: [0,16K) w0 | [16K,32K) w1 | [32K,35K) sh
__device__ __forceinline__ void node_fctp_body(
    int blk, int path,
    const float* __restrict__ s, const float* __restrict__ v,
    const float* __restrict__ attr, const float* __restrict__ Wfp,
    float* __restrict__ sc_s, float* __restrict__ sc_v,
    float* __restrict__ xsv, int N, char* smem) {
    float* w0 = (float*)smem;
    float* w1 = (float*)(smem + 16384);
    float (*sh)[96] = (float(*)[96])(smem + 32768);
    int ln = threadIdx.x >> 5, w = threadIdx.x & 31;
    const float4* W0p = (const float4*)(Wfp + path * 8192);
    const float4* W1p = (const float4*)(Wfp + path * 8192 + 4096);
    for (int i = threadIdx.x; i < 1024; i += 256) {
        ((float4*)w0)[i] = W0p[i];
        ((float4*)w1)[i] = W1p[i];
    }
    for (int g = 0; g < 2; g++) {
        int n = blk * 16 + g * 8 + ln;
        bool valid = n < N;
        __syncthreads();
        if (valid) {
            if (path == 0) {
                sh[ln][w] = s[n * 32 + w];
            } else {
                sh[ln][w * 3 + 0] = v[n * 96 + w * 3 + 0];
                sh[ln][w * 3 + 1] = v[n * 96 + w * 3 + 1];
                sh[ln][w * 3 + 2] = v[n * 96 + w * 3 + 2];
            }
        }
        __syncthreads();
        if (!valid) continue;
        float4 at = *(const float4*)(attr + n * 4);
        if (path == 0) {
            float acc0 = 0.f, acc1 = 0.f;
            for (int u = 0; u < 32; u++) {
                float su = sh[ln][u];
                float4 W0v = *(const float4*)(w0 + u * 128 + w * 4);
                float4 W1v = *(const float4*)(w1 + u * 128 + w * 4);
                float d0 = at.x * W0v.x + at.y * W0v.y + at.z * W0v.z + at.w * W0v.w;
                float d1 = at.x * W1v.x + at.y * W1v.y + at.z * W1v.z + at.w * W1v.w;
                acc0 += su * d0;
                acc1 += su * d1;
            }
            sc_s[n * 32 + w] = acc0 * NORM128_F;
            xsv[(size_t)n * 128 + w * 4 + 3] = acc1 * NORM128_F;
        } else {
            float a00 = 0, a01 = 0, a02 = 0, a10 = 0, a11 = 0, a12 = 0;
            for (int u = 0; u < 32; u++) {
                float vu0 = sh[ln][u * 3 + 0];
                float vu1 = sh[ln][u * 3 + 1];
                float vu2 = sh[ln][u * 3 + 2];
                float4 W0v = *(const float4*)(w0 + u * 128 + w * 4);
                float4 W1v = *(const float4*)(w1 + u * 128 + w * 4);
                float d0 = at.x * W0v.x + at.y * W0v.y + at.z * W0v.z + at.w * W0v.w;
                float d1 = at.x * W1v.x + at.y * W1v.y + at.z * W1v.z + at.w * W1v.w;
                a00 += vu0 * d0; a01 += vu1 * d0; a02 += vu2 * d0;
                a10 += vu0 * d1; a11 += vu1 * d1; a12 += vu2 * d1;
            }
            sc_v[n * 96 + w * 3 + 0] = a00 * NORM128_F;
            sc_v[n * 96 + w * 3 + 1] = a01 * NORM128_F;
            sc_v[n * 96 + w * 3 + 2] = a02 * NORM128_F;
            float* xp = xsv + (size_t)n * 128 + w * 4;
            xp[0] = a10 * NORM128_F;
            xp[1] = a11 * NORM128_F;
            xp[2] = a12 * NORM128_F;
        }
    }
}

// ---------------------------------------------------------------- mega kernels
// tab blocks FIRST so the table generation starts immediately.
__global__ __launch_bounds__(256) void mega1(
    int nTab, int nInit, int nSetup,
    const float* __restrict__ x, float* __restrict__ s, float* __restrict__ v,
    const float* __restrict__ Wfc1, const float* __restrict__ Wfc2,
    const float* __restrict__ Wsc0, const float* __restrict__ Wl10,
    const float* __restrict__ Wsc1, const float* __restrict__ Wl11,
    const float* __restrict__ Wl20, const float* __restrict__ Wl21,
    float* __restrict__ Wfp, unsigned* __restrict__ Wupk,
    unsigned* __restrict__ tab,
    const int* __restrict__ edst, int* __restrict__ cnt, int N, int E) {
    __shared__ float sh_h[4][64];
    int b = blockIdx.x;
    if (b < nTab) { tab_gen_body(b, Wfc1, Wfc2, tab, sh_h); return; }
    b -= nTab;
    if (b < nInit) { init_sv_body(b, x, s, v, N); return; }
    b -= nInit;
    if (b < nSetup) {
        setup_weights_body(b, Wsc0, Wl10, Wsc1, Wl11, Wl20, Wl21, Wfp, Wupk);
        return;
    }
    b -= nSetup;
    csr_count_body(b, edst, cnt, E);
}

__global__ void csr_scan(const int* __restrict__ cnt, int* __restrict__ off,
                         int* __restrict__ cursor, int N) {
    __shared__ int sums[256];
    int t = threadIdx.x;
    int chunk = (N + 255) / 256;
    int lo = t * chunk, hi = lo + chunk; if (hi > N) hi = N;
    int s = 0;
    for (int i = lo; i < hi; i++) s += cnt[i];
    sums[t] = s;
    __syncthreads();
    for (int d = 1; d < 256; d <<= 1) {
        int v = (t >= d) ? sums[t - d] : 0;
        __syncthreads();
        sums[t] += v;
        __syncthreads();
    }
    int run = (t == 0) ? 0 : sums[t - 1];
    for (int i = lo; i < hi; i++) {
        off[i] = run; cursor[i] = run;
        run += cnt[i];
    }
}

// csr_fill || fctp(layer0, both paths) || tab4 conversion
__global__ __launch_bounds__(256, 4) void mega2(
    int nFill, int nF,
    const int* __restrict__ edst, const int* __restrict__ esrc,
    const float* __restrict__ edge_vec, int* __restrict__ cursor,
    float* __restrict__ vec_csr, unsigned* __restrict__ tifr, int E,
    const float* __restrict__ s, const float* __restrict__ v,
    const float* __restrict__ attr, const float* __restrict__ Wfp,
    float* __restrict__ sc_s, float* __restrict__ sc_v,
    float* __restrict__ xsv, int N,
    const unsigned* __restrict__ tab, unsigned* __restrict__ tab4) {
    __shared__ __align__(16) char smem[35840];
    int b = blockIdx.x;
    if (b < nFill) {
        csr_fill_body(b, edst, esrc, edge_vec, cursor, vec_csr, tifr, E);
        return;
    }
    b -= nFill;
    if (b < 2 * nF) {
        node_fctp_body(b % nF, b / nF, s, v, attr, Wfp, sc_s, sc_v, xsv, N, smem);
        return;
    }
    b -= 2 * nF;
    tab4_body(b, tab, tab4);
}

// next-layer fctp (both paths) as a standalone dispatch
__global__ __launch_bounds__(256, 4) void fctp_only(
    int nF,
    const float* __restrict__ s, const float* __restrict__ v,
    const float* __restrict__ attr, const float* __restrict__ Wfp,
    float* __restrict__ sc_s, float* __restrict__ sc_v,
    float* __restrict__ xsv, int N) {
    __shared__ __align__(16) char smem[35840];
    node_fctp_body(blockIdx.x % nF, blockIdx.x / nF, s, v, attr, Wfp,
                   sc_s, sc_v, xsv, N, smem);
}

// ---------------------------------------------------------------- gather+update
// 2 nodes/block, 128 threads each (4 quarter-waves striding slots by 4).
// Edge weights from the delta-form tab4 (one dwordx4 per edge-lane: value+delta,
// lerp = 4 fma). y/ti/fr precomputed in csr_fill. Agg stays in LDS; update phase
// runs wave-parallel (quarter q covers 16 of 64 uu-terms). No atomics anywhere.
__global__ __launch_bounds__(256, 4) void gather_update(
    const int* __restrict__ off, const int* __restrict__ cnt,
    const unsigned* __restrict__ tab4,
    const float* __restrict__ vec_csr, const unsigned* __restrict__ tifr,
    const float* __restrict__ xsv,
    const float* __restrict__ attr, const unsigned* __restrict__ Wupk,
    const float* __restrict__ sc_s, const float* __restrict__ sc_v,
    float* __restrict__ s, float* __restrict__ v, int N) {
    __shared__ float red[2][8][32];
    __shared__ float part[2][4][32];
    int pair = threadIdx.x >> 7;
    int node = blockIdx.x * 2 + pair;
    int ql = threadIdx.x & 127;
    int quarter = ql >> 5;
    int u = ql & 31;
    bool active = node < N;
    int o = 0, deg = 0;
    if (active) { o = off[node]; deg = cnt[node]; }
    float as0 = 0, as1 = 0;
    float av00 = 0, av01 = 0, av02 = 0, av10 = 0, av11 = 0, av12 = 0;

    auto body = [&](int slot) {
        size_t p = (size_t)slot;
        float4 vv = *(const float4*)(vec_csr + p * 4);   // y0,y1,y2,src
        int src = __float_as_int(vv.w);
        uint2 tf = *(const uint2*)(tifr + p * 2);
        int ti = (int)tf.x;
        float fr = __uint_as_float(tf.y);
        uint4 tq = ((const uint4*)tab4)[((size_t)ti << 5) + u];
        float4 x4 = *(const float4*)(xsv + (size_t)src * 128 + u * 4);
        float wa = bf2f((unsigned short)tq.x) + fr * bf2f((unsigned short)tq.z);
        float wc = bf2f((unsigned short)(tq.x >> 16)) + fr * bf2f((unsigned short)(tq.z >> 16));
        float wb = bf2f((unsigned short)tq.y) + fr * bf2f((unsigned short)tq.w);
        float wd = bf2f((unsigned short)(tq.y >> 16)) + fr * bf2f((unsigned short)(tq.w >> 16));
        as0 += wa * x4.w;
        as1 += wb * (vv.x * x4.x + vv.y * x4.y + vv.z * x4.z) * INV_SQRT3_F;
        float tt = wc * x4.w;
        av00 += tt * vv.x;  av01 += tt * vv.y;  av02 += tt * vv.z;
        av10 += wd * x4.x; av11 += wd * x4.y; av12 += wd * x4.z;
    };

    int i = quarter;
    for (; i + 4 < deg; i += 8) { body(o + i); body(o + i + 4); }
    for (; i < deg; i += 4) body(o + i);

    as0 += __shfl_down(as0, 32);  as1 += __shfl_down(as1, 32);
    av00 += __shfl_down(av00, 32); av01 += __shfl_down(av01, 32); av02 += __shfl_down(av02, 32);
    av10 += __shfl_down(av10, 32); av11 += __shfl_down(av11, 32); av12 += __shfl_down(av12, 32);

    int lane = threadIdx.x & 63;
    int upper_wave = (threadIdx.x >> 6) & 1;
    if (upper_wave && lane < 32) {
        red[pair][0][u] = as0;  red[pair][1][u] = as1;
        red[pair][2][u] = av00; red[pair][3][u] = av01; red[pair][4][u] = av02;
        red[pair][5][u] = av10; red[pair][6][u] = av11; red[pair][7][u] = av12;
    }
    __syncthreads();
    if (!upper_wave && lane < 32) {
        // final scaled agg vector -> red
        red[pair][0][u] = (as0 + red[pair][0][u]) * INV_SQRTNN_F;   // agg_s[u]
        red[pair][1][u] = (as1 + red[pair][1][u]) * INV_SQRTNN_F;   // agg_s[32+u]
        red[pair][2][u] = (av00 + red[pair][2][u]) * INV_SQRTNN_F;  // agg_v[u][.]
        red[pair][3][u] = (av01 + red[pair][3][u]) * INV_SQRTNN_F;
        red[pair][4][u] = (av02 + red[pair][4][u]) * INV_SQRTNN_F;
        red[pair][5][u] = (av10 + red[pair][5][u]) * INV_SQRTNN_F;  // agg_v[32+u][.]
        red[pair][6][u] = (av11 + red[pair][6][u]) * INV_SQRTNN_F;
        red[pair][7][u] = (av12 + red[pair][7][u]) * INV_SQRTNN_F;
    }
    __syncthreads();

    // ---- update phase: all 128 threads/node; quarter q covers uu in
    // [q*16,(q+1)*16); shfl+LDS reduce the 4 partials; lower-wave finalizes.
    {
        int half = quarter >> 1;            // uu<32 for q0,q1; uu>=32 for q2,q3
        int ub = (quarter & 1) * 16;        // within-half base
        int w = u;
        float4 at = {0.f, 0.f, 0.f, 0.f};
        if (active) at = *(const float4*)(attr + node * 4);
        const float* rs = red[pair][half];
        const float* r0 = red[pair][2 + 3 * half];
        const float* r1 = red[pair][3 + 3 * half];
        const float* r2 = red[pair][4 + 3 * half];
        float pacc = 0.f, pa0 = 0.f, pa1 = 0.f, pa2 = 0.f;
#pragma unroll
        for (int k = 0; k < 16; k++) {
            int j = ub + k;                 // index within half, 0..31
            float gs = rs[j], g0 = r0[j], g1 = r1[j], g2 = r2[j];
            uint4 pv = *(const uint4*)(Wupk + (half * 32 + j) * 128 + w * 4);
            float w20x = bf2f((unsigned short)pv.x), w21x = bf2f((unsigned short)(pv.x >> 16));
            float w20y = bf2f((unsigned short)pv.y), w21y = bf2f((unsigned short)(pv.y >> 16));
            float w20z = bf2f((unsigned short)pv.z), w21z = bf2f((unsigned short)(pv.z >> 16));
            float w20w = bf2f((unsigned short)pv.w), w21w = bf2f((unsigned short)(pv.w >> 16));
            float d0 = at.x * w20x + at.y * w20y + at.z * w20z + at.w * w20w;
            float d1 = at.x * w21x + at.y * w21y + at.z * w21z + at.w * w21w;
            pacc += gs * d0;
            pa0 += g0 * d1; pa1 += g1 * d1; pa2 += g2 * d1;
        }
        pacc += __shfl_down(pacc, 32);
        pa0 += __shfl_down(pa0, 32);
        pa1 += __shfl_down(pa1, 32);
        pa2 += __shfl_down(pa2, 32);
        if (upper_wave && lane < 32) {
            part[pair][0][u] = pacc;
            part[pair][1][u] = pa0;
            part[pair][2][u] = pa1;
            part[pair][3][u] = pa2;
        }
        __syncthreads();
        if (active && !upper_wave && lane < 32) {
            pacc += part[pair][0][u];
            pa0 += part[pair][1][u];
            pa1 += part[pair][2][u];
            pa2 += part[pair][3][u];
            float os = pacc * NORM256_F;
            float sn = C_S_F * sc_s[node * 32 + w] + C_X_F * os;
            float sig = 1.0f / (1.0f + __expf(-sn));
            s[node * 32 + w] += sn * sig;   // silu(sn)
            float ov0 = pa0 * NORM256_F, ov1 = pa1 * NORM256_F, ov2 = pa2 * NORM256_F;
            v[node * 96 + w * 3 + 0] += (C_S_F * sc_v[node * 96 + w * 3 + 0] + C_X_F * ov0) * sig;
            v[node * 96 + w * 3 + 1] += (C_S_F * sc_v[node * 96 + w * 3 + 1] + C_X_F * ov1) * sig;
            v[node * 96 + w * 3 + 2] += (C_S_F * sc_v[node * 96 + w * 3 + 2] + C_X_F * ov2) * sig;
        }
    }
}

// ---------------------------------------------------------------- readout
__global__ __launch_bounds__(256) void readout(
    const float* __restrict__ s, const float* __restrict__ attr,
    const float* __restrict__ Wread, const int* __restrict__ batch,
    float* __restrict__ out, int N, float pool_scale) {
    __shared__ float wr[2048];
    __shared__ float red[NGRAPH * 16];
    for (int i = threadIdx.x; i < 2048; i += 256) wr[i] = Wread[i];
    if (threadIdx.x < NGRAPH * 16) red[threadIdx.x] = 0.f;
    __syncthreads();
    int ln = threadIdx.x >> 4, w = threadIdx.x & 15;
    for (int g = 0; g < 4; g++) {
        int n = blockIdx.x * 64 + g * 16 + ln;
        if (n < N) {
            float4 at = *(const float4*)(attr + n * 4);
            float fa[4] = {at.x, at.y, at.z, at.w};
            float acc = 0.f;
            for (int u = 0; u < 32; u++) {
                float su = s[n * 32 + u];
                int base = u * 64 + w;
#pragma unroll
                for (int a = 0; a < 4; a++) acc += su * fa[a] * wr[base + a * 16];
            }
            atomicAdd(&red[batch[n] * 16 + w], acc);
        }
    }
    __syncthreads();
    if (threadIdx.x < NGRAPH * 16) {
        float val = red[threadIdx.x];
        if (val != 0.f)
            atomicAdd(&out[threadIdx.x], val * NORM128_F * pool_scale);
    }
}

// ---------------------------------------------------------------- launch
extern "C" void kernel_launch(void* const* d_in, const int* in_sizes, int n_in,
                              void* d_out, int out_size, void* d_ws, size_t ws_size,
                              hipStream_t stream) {
    const float* x        = (const float*)d_in[0];
    const float* nattr    = (const float*)d_in[1];
    const float* edge_vec = (const float*)d_in[2];
    const int*   batch    = (const int*)d_in[3];
    const int*   esrc     = (const int*)d_in[4];
    const int*   edst     = (const int*)d_in[5];
    const float* Wsc0  = (const float*)d_in[6];
    const float* Wsc1  = (const float*)d_in[7];
    const float* Wl10  = (const float*)d_in[8];
    const float* Wl11  = (const float*)d_in[9];
    const float* Wfc1  = (const float*)d_in[10];
    const float* Wfc2  = (const float*)d_in[11];
    const float* Wl20  = (const float*)d_in[12];
    const float* Wl21  = (const float*)d_in[13];
    const float* Wread = (const float*)d_in[14];

    int N = in_sizes[0] / (MUL * 4);
    int E = in_sizes[2] / 3;

    float* p = (float*)d_ws;
    float* vec_csr = p; p += (size_t)E * 4;     // {y0,y1,y2,src-bits}
    unsigned* tifr = (unsigned*)p; p += ((size_t)E * 2 + 3) & ~(size_t)3;  // {ti,fr}/slot
    unsigned* tab = (unsigned*)p; p += 2 * NT * 64;  // w(len) tables, packed bf16
    unsigned* tab4 = (unsigned*)p; p += 2 * 512 * 32 * 4;  // delta-form tables
    float* Wfp    = p; p += 32768;              // 2 layers x 4 matrices x 4096
    unsigned* Wupk = (unsigned*)p; p += 16384;  // 2 layers x 8192 packed pair dwords
    float* s_buf  = p; p += (size_t)N * 32;
    float* v_buf  = p; p += (size_t)N * 96;
    float* sc_s   = p; p += (size_t)N * 32;
    float* sc_v   = p; p += (size_t)N * 96;
    float* xsv    = p; p += (size_t)N * 128;    // {xv0,xv1,xv2,xs} per (n,u)
    int* cnt     = (int*)p; p += N;
    int* off     = (int*)p; p += N;
    int* cursor  = (int*)p; p += N;

    hipMemsetAsync(d_out, 0, (size_t)out_size * sizeof(float), stream);
    hipMemsetAsync(cnt, 0, (size_t)N * sizeof(int), stream);

    int nTab   = (2 * NT + 3) / 4;              // 4 rows per block
    int nInit  = (N * 128 + 255) / 256;
    int nSetup = 192;
    int nCount = (E + 255) / 256;
    mega1<<<nTab + nInit + nSetup + nCount, 256, 0, stream>>>(
        nTab, nInit, nSetup, x, s_buf, v_buf,
        Wfc1, Wfc2, Wsc0, Wl10, Wsc1, Wl11, Wl20, Wl21,
        Wfp, Wupk, tab, edst, cnt, N, E);

    csr_scan<<<1, 256, 0, stream>>>(cnt, off, cursor, N);

    int nFill = (E + 255) / 256;
    int nF = (N + 15) / 16;
    int nConv = (2 * 512 * 32 + 255) / 256;     // tab4 converter blocks
    mega2<<<nFill + 2 * nF + nConv, 256, 0, stream>>>(
        nFill, nF, edst, esrc, edge_vec, cursor, vec_csr, tifr, E,
        s_buf, v_buf, nattr, Wfp, sc_s, sc_v, xsv, N, tab, tab4);

    int nG = (N + 1) / 2;

    // ---- layer 0: gather+update fused, then next-layer fctp
    gather_update<<<nG, 256, 0, stream>>>(
        off, cnt, tab4, vec_csr, tifr, xsv, nattr, Wupk,
        sc_s, sc_v, s_buf, v_buf, N);
    fctp_only<<<2 * nF, 256, 0, stream>>>(
        nF, s_buf, v_buf, nattr, Wfp + 16384, sc_s, sc_v, xsv, N);

    // ---- layer 1: gather+update fused (no further fctp)
    gather_update<<<nG, 256, 0, stream>>>(
        off, cnt, tab4 + 512 * 32 * 4, vec_csr, tifr, xsv, nattr, Wupk + 8192,
        sc_s, sc_v, s_buf, v_buf, N);

    float pool_scale = (float)(1.0 / sqrt((double)N / (double)NGRAPH));
    readout<<<(N + 63) / 64, 256, 0, stream>>>(
        s_buf, nattr, Wread, batch, (float*)d_out, N, pool_scale);
}

// Round 15
// 257.577 us; speedup vs baseline: 1.1968x; 1.0731x over previous
//
#include <hip/hip_runtime.h>
#include <math.h>

#define MUL 32
#define NATTR 4
#define NBASIS 10
#define HID 64
#define OUT_DIM 16
#define NGRAPH 8
#define NT 513      // w(len) table entries: len = i/128, i in [0,512]

#define PI_F 3.14159265358979323846f
#define SQRT3_F 1.7320508075688772f
#define INV_SQRT3_F 0.5773502691896258f
#define INV_SQRT10_F 0.31622776601683794f
#define INV_SQRTNN_F 0.17677669529663687f   // 1/sqrt(32)
#define NORM128_F 0.08838834764831845f      // 1/sqrt(128)
#define NORM256_F 0.0625f                   // 1/sqrt(256)
#define C_S_F 0.3826834323650898f           // sin(pi/8)
#define C_X_F 0.9238795325112867f           // cos(pi/8)
#define CSTEP_F (4.0f/9.0f)                 // linspace(0,4,10) step

__device__ inline unsigned short f2bf(float x) {
    unsigned u = __float_as_uint(x);
    u += 0x7FFF + ((u >> 16) & 1);          // round-to-nearest-even
    return (unsigned short)(u >> 16);
}
__device__ inline float bf2f(unsigned short h) {
    return __uint_as_float(((unsigned)h) << 16);
}
__device__ inline float bf2f_lo(unsigned x) {       // low bf16 of packed pair
    return __uint_as_float(x << 16);
}
__device__ inline float bf2f_hi(unsigned x) {       // high bf16 of packed pair
    return __uint_as_float(x & 0xFFFF0000u);
}

// ---------------------------------------------------------------- bodies
__device__ __forceinline__ void init_sv_body(
    int blk, const float* __restrict__ x,
    float* __restrict__ s, float* __restrict__ v, int N) {
    int i = blk * 256 + threadIdx.x;
    if (i >= N * 128) return;
    int n = i >> 7, c = i & 127;
    float val = x[i];
    if (c < 32) s[n * 32 + c] = val;
    else        v[n * 96 + (c - 32)] = val;
}

__device__ __forceinline__ void setup_weights_body(
    int blk,
    const float* __restrict__ Wsc0, const float* __restrict__ Wl10,
    const float* __restrict__ Wsc1, const float* __restrict__ Wl11,
    const float* __restrict__ Wl20, const float* __restrict__ Wl21,
    float* __restrict__ Wfp, unsigned* __restrict__ Wupk) {
    int i = blk * 256 + threadIdx.x;
    if (i < 32768) {
        int idx = i >> 12;          // l*4 + m
        int r = i & 4095;
        int l = idx >> 2, m = idx & 3;
        const float* base = (m == 0 ? Wsc0 : m == 1 ? Wl10 : m == 2 ? Wsc1 : Wl11)
                            + l * 4096;
        int u = r >> 7, rr = r & 127, a = rr >> 5, ww = rr & 31;
        Wfp[idx * 4096 + u * 128 + ww * 4 + a] = base[r];
    } else if (i < 49152) {
        int j = i - 32768;
        int l = j >> 13;
        int r = j & 8191;
        int u = r >> 7, rr = r & 127, a = rr >> 5, ww = rr & 31;
        unsigned lo = f2bf(Wl20[l * 8192 + r]);
        unsigned hi = f2bf(Wl21[l * 8192 + r]);
        Wupk[l * 8192 + u * 128 + ww * 4 + a] = lo | (hi << 16);
    }
}

// w(len) table generator, cooperative: one 64-thread group per table row.
__device__ __forceinline__ void tab_gen_body(
    int blk, const float* __restrict__ Wfc1, const float* __restrict__ Wfc2,
    unsigned* __restrict__ tab, float (*sh_h)[64]) {
    int g = threadIdx.x >> 6;       // row group 0..3
    int n = threadIdx.x & 63;       // h index / output j
    int row = blk * 4 + g;
    bool valid = row < 2 * NT;
    int l = valid ? row / NT : 0;
    int i = valid ? row % NT : 0;
    float len = (float)i * (1.0f / 128.0f);
    float uu = len * 0.5f - 2.0f;
    float cut = (uu > 0.0f) ? 0.0f
              : ((uu < -1.0f) ? 1.0f : 0.5f * (1.0f - __cosf(PI_F * uu)));
    const float* W1 = Wfc1 + l * 640;
    float a = 0.f;
#pragma unroll
    for (int k = 0; k < 10; k++) {
        float d = (len - k * CSTEP_F) * 2.5f;
        float e = __expf(-d * d) * cut;
        a += e * W1[k * 64 + n];
    }
    a *= INV_SQRT10_F;
    sh_h[g][n] = a / (1.0f + __expf(-a));
    __syncthreads();
    if (!valid) return;
    const float* W2 = Wfc2 + l * 8192;
    float w0 = 0.f, w1 = 0.f;
#pragma unroll 8
    for (int nn = 0; nn < 64; nn++) {
        float hn = sh_h[g][nn];
        w0 += hn * W2[nn * 128 + n];
        w1 += hn * W2[nn * 128 + 64 + n];
    }
    w0 *= 0.125f; w1 *= 0.125f;
    tab[(size_t)l * NT * 64 + i * 64 + n] =
        (unsigned)f2bf(w0) | ((unsigned)f2bf(w1) << 16);
}

// tab4 converter: tab4[l][ti][u] (uint4, ti in [0,512), u in [0,32)) =
// { tab[ti][u], tab[ti][u+32], pk(delta lo/hi of col u), pk(delta of u+32) }
__device__ __forceinline__ void tab4_body(
    int blk, const unsigned* __restrict__ tab, unsigned* __restrict__ tab4) {
    int id = blk * 256 + threadIdx.x;
    if (id >= 2 * 512 * 32) return;
    int l = id >> 14;
    int r = id & 16383;
    int ti = r >> 5, u = r & 31;
    const unsigned* tb = tab + (size_t)l * NT * 64 + ti * 64;
    unsigned a0 = tb[u],      a1 = tb[u + 32];
    unsigned b0 = tb[64 + u], b1 = tb[64 + u + 32];
    float d0l = bf2f((unsigned short)b0) - bf2f((unsigned short)a0);
    float d0h = bf2f((unsigned short)(b0 >> 16)) - bf2f((unsigned short)(a0 >> 16));
    float d1l = bf2f((unsigned short)b1) - bf2f((unsigned short)a1);
    float d1h = bf2f((unsigned short)(b1 >> 16)) - bf2f((unsigned short)(a1 >> 16));
    uint4 q;
    q.x = a0;
    q.y = a1;
    q.z = (unsigned)f2bf(d0l) | ((unsigned)f2bf(d0h) << 16);
    q.w = (unsigned)f2bf(d1l) | ((unsigned)f2bf(d1h) << 16);
    ((uint4*)tab4)[((size_t)l * 512 + ti) * 32 + u] = q;
}

__device__ __forceinline__ void csr_count_body(
    int blk, const int* __restrict__ edst, int* __restrict__ cnt, int E) {
    int e = blk * 256 + threadIdx.x;
    if (e < E) atomicAdd(&cnt[edst[e]], 1);
}

// csr_fill: pre-normalize y (= sqrt3 * unit) and precompute {ti, fr} per slot.
__device__ __forceinline__ void csr_fill_body(
    int blk, const int* __restrict__ edst, const int* __restrict__ esrc,
    const float* __restrict__ edge_vec, int* __restrict__ cursor,
    float* __restrict__ vec_csr, unsigned* __restrict__ tifr, int E) {
    int e = blk * 256 + threadIdx.x;
    if (e < E) {
        int d = edst[e];
        int p = atomicAdd(&cursor[d], 1);
        float ex = edge_vec[e * 3 + 0], ey = edge_vec[e * 3 + 1], ez = edge_vec[e * 3 + 2];
        float len = sqrtf(ex * ex + ey * ey + ez * ez);
        float rinv = SQRT3_F / (len + 1e-9f);
        float t = fminf(len, 3.99995f) * 128.0f;
        int ti = (int)t;
        float fr = t - (float)ti;
        float4 vv = {ex * rinv, ey * rinv, ez * rinv, __int_as_float(esrc[e])};
        *(float4*)(vec_csr + (size_t)p * 4) = vv;
        uint2 tf = {(unsigned)ti, __float_as_uint(fr)};
        *(uint2*)(tifr + (size_t)p * 2) = tf;
    }
}

// node fctp: 16 nodes/block; smem: [0,16K) w0 | [16K,32K) w1 | [32K,35K) sh
__device__ __forceinline__ void node_fctp_body(
    int blk, int path,
    const float* __restrict__ s, const float* __restrict__ v,
    const float* __restrict__ attr, const float* __restrict__ Wfp,
    float* __restrict__ sc_s, float* __restrict__ sc_v,
    float* __restrict__ xsv, int N, char* smem) {
    float* w0 = (float*)smem;
    float* w1 = (float*)(smem + 16384);
    float (*sh)[96] = (float(*)[96])(smem + 32768);
    int ln = threadIdx.x >> 5, w = threadIdx.x & 31;
    const float4* W0p = (const float4*)(Wfp + path * 8192);
    const float4* W1p = (const float4*)(Wfp + path * 8192 + 4096);
    for (int i = threadIdx.x; i < 1024; i += 256) {
        ((float4*)w0)[i] = W0p[i];
        ((float4*)w1)[i] = W1p[i];
    }
    for (int g = 0; g < 2; g++) {
        int n = blk * 16 + g * 8 + ln;
        bool valid = n < N;
        __syncthreads();
        if (valid) {
            if (path == 0) {
                sh[ln][w] = s[n * 32 + w];
            } else {
                sh[ln][w * 3 + 0] = v[n * 96 + w * 3 + 0];
                sh[ln][w * 3 + 1] = v[n * 96 + w * 3 + 1];
                sh[ln][w * 3 + 2] = v[n * 96 + w * 3 + 2];
            }
        }
        __syncthreads();
        if (!valid) continue;
        float4 at = *(const float4*)(attr + n * 4);
        if (path == 0) {
            float acc0 = 0.f, acc1 = 0.f;
            for (int u = 0; u < 32; u++) {
                float su = sh[ln][u];
                float4 W0v = *(const float4*)(w0 + u * 128 + w * 4);
                float4 W1v = *(const float4*)(w1 + u * 128 + w * 4);
                float d0 = at.x * W0v.x + at.y * W0v.y + at.z * W0v.z + at.w * W0v.w;
                float d1 = at.x * W1v.x + at.y * W1v.y + at.z * W1v.z + at.w * W1v.w;
                acc0 += su * d0;
                acc1 += su * d1;
            }
            sc_s[n * 32 + w] = acc0 * NORM128_F;
            xsv[(size_t)n * 128 + w * 4 + 3] = acc1 * NORM128_F;
        } else {
            float a00 = 0, a01 = 0, a02 = 0, a10 = 0, a11 = 0, a12 = 0;
            for (int u = 0; u < 32; u++) {
                float vu0 = sh[ln][u * 3 + 0];
                float vu1 = sh[ln][u * 3 + 1];
                float vu2 = sh[ln][u * 3 + 2];
                float4 W0v = *(const float4*)(w0 + u * 128 + w * 4);
                float4 W1v = *(const float4*)(w1 + u * 128 + w * 4);
                float d0 = at.x * W0v.x + at.y * W0v.y + at.z * W0v.z + at.w * W0v.w;
                float d1 = at.x * W1v.x + at.y * W1v.y + at.z * W1v.z + at.w * W1v.w;
                a00 += vu0 * d0; a01 += vu1 * d0; a02 += vu2 * d0;
                a10 += vu0 * d1; a11 += vu1 * d1; a12 += vu2 * d1;
            }
            sc_v[n * 96 + w * 3 + 0] = a00 * NORM128_F;
            sc_v[n * 96 + w * 3 + 1] = a01 * NORM128_F;
            sc_v[n * 96 + w * 3 + 2] = a02 * NORM128_F;
            float* xp = xsv + (size_t)n * 128 + w * 4;
            xp[0] = a10 * NORM128_F;
            xp[1] = a11 * NORM128_F;
            xp[2] = a12 * NORM128_F;
        }
    }
}

// ---------------------------------------------------------------- mega kernels
// tab blocks FIRST so the table generation starts immediately.
__global__ __launch_bounds__(256) void mega1(
    int nTab, int nInit, int nSetup,
    const float* __restrict__ x, float* __restrict__ s, float* __restrict__ v,
    const float* __restrict__ Wfc1, const float* __restrict__ Wfc2,
    const float* __restrict__ Wsc0, const float* __restrict__ Wl10,
    const float* __restrict__ Wsc1, const float* __restrict__ Wl11,
    const float* __restrict__ Wl20, const float* __restrict__ Wl21,
    float* __restrict__ Wfp, unsigned* __restrict__ Wupk,
    unsigned* __restrict__ tab,
    const int* __restrict__ edst, int* __restrict__ cnt, int N, int E) {
    __shared__ float sh_h[4][64];
    int b = blockIdx.x;
    if (b < nTab) { tab_gen_body(b, Wfc1, Wfc2, tab, sh_h); return; }
    b -= nTab;
    if (b < nInit) { init_sv_body(b, x, s, v, N); return; }
    b -= nInit;
    if (b < nSetup) {
        setup_weights_body(b, Wsc0, Wl10, Wsc1, Wl11, Wl20, Wl21, Wfp, Wupk);
        return;
    }
    b -= nSetup;
    csr_count_body(b, edst, cnt, E);
}

// Parallel CSR slot allocation: per-wave64 inclusive shfl-scan of cnt, one
// atomicAdd per wave for the base. Slot order across waves is arbitrary —
// every consumer is order-independent (per-node sums). Replaces the serial
// single-block prefix scan.
__global__ __launch_bounds__(256) void csr_alloc(
    const int* __restrict__ cnt, int* __restrict__ off,
    int* __restrict__ cursor, int* __restrict__ gcur, int N) {
    int i = blockIdx.x * 256 + threadIdx.x;
    int lane = threadIdx.x & 63;
    int c = (i < N) ? cnt[i] : 0;
    int sc = c;
#pragma unroll
    for (int d = 1; d < 64; d <<= 1) {
        int t = __shfl_up(sc, d);
        if (lane >= d) sc += t;
    }
    int total = __shfl(sc, 63);
    int base = 0;
    if (lane == 0) base = atomicAdd(gcur, total);
    base = __shfl(base, 0);
    if (i < N) {
        int o = base + sc - c;      // exclusive position
        off[i] = o;
        cursor[i] = o;
    }
}

// csr_fill || fctp(layer0, both paths) || tab4 conversion
__global__ __launch_bounds__(256, 4) void mega2(
    int nFill, int nF,
    const int* __restrict__ edst, const int* __restrict__ esrc,
    const float* __restrict__ edge_vec, int* __restrict__ cursor,
    float* __restrict__ vec_csr, unsigned* __restrict__ tifr, int E,
    const float* __restrict__ s, const float* __restrict__ v,
    const float* __restrict__ attr, const float* __restrict__ Wfp,
    float* __restrict__ sc_s, float* __restrict__ sc_v,
    float* __restrict__ xsv, int N,
    const unsigned* __restrict__ tab, unsigned* __restrict__ tab4) {
    __shared__ __align__(16) char smem[35840];
    int b = blockIdx.x;
    if (b < nFill) {
        csr_fill_body(b, edst, esrc, edge_vec, cursor, vec_csr, tifr, E);
        return;
    }
    b -= nFill;
    if (b < 2 * nF) {
        node_fctp_body(b % nF, b / nF, s, v, attr, Wfp, sc_s, sc_v, xsv, N, smem);
        return;
    }
    b -= 2 * nF;
    tab4_body(b, tab, tab4);
}

// next-layer fctp (both paths) as a standalone dispatch
__global__ __launch_bounds__(256, 4) void fctp_only(
    int nF,
    const float* __restrict__ s, const float* __restrict__ v,
    const float* __restrict__ attr, const float* __restrict__ Wfp,
    float* __restrict__ sc_s, float* __restrict__ sc_v,
    float* __restrict__ xsv, int N) {
    __shared__ __align__(16) char smem[35840];
    node_fctp_body(blockIdx.x % nF, blockIdx.x / nF, s, v, attr, Wfp,
                   sc_s, sc_v, xsv, N, smem);
}

// ---------------------------------------------------------------- gather+update
// 2 nodes/block, 128 threads each (4 quarter-waves striding slots by 4).
// Edge weights from the delta-form tab4 (one dwordx4 per edge-lane: value+delta,
// lerp = 4 fma). y/ti/fr precomputed in csr_fill. Agg stays in LDS; update phase
// runs wave-parallel (quarter q covers 16 of 64 uu-terms). No atomics anywhere.
__global__ __launch_bounds__(256, 4) void gather_update(
    const int* __restrict__ off, const int* __restrict__ cnt,
    const unsigned* __restrict__ tab4,
    const float* __restrict__ vec_csr, const unsigned* __restrict__ tifr,
    const float* __restrict__ xsv,
    const float* __restrict__ attr, const unsigned* __restrict__ Wupk,
    const float* __restrict__ sc_s, const float* __restrict__ sc_v,
    float* __restrict__ s, float* __restrict__ v, int N) {
    __shared__ float red[2][8][32];
    __shared__ float part[2][4][32];
    int pair = threadIdx.x >> 7;
    int node = blockIdx.x * 2 + pair;
    int ql = threadIdx.x & 127;
    int quarter = ql >> 5;
    int u = ql & 31;
    bool active = node < N;
    int o = 0, deg = 0;
    if (active) { o = off[node]; deg = cnt[node]; }
    float as0 = 0, as1 = 0;
    float av00 = 0, av01 = 0, av02 = 0, av10 = 0, av11 = 0, av12 = 0;

    auto body = [&](int slot) {
        size_t p = (size_t)slot;
        float4 vv = *(const float4*)(vec_csr + p * 4);   // y0,y1,y2,src
        int src = __float_as_int(vv.w);
        uint2 tf = *(const uint2*)(tifr + p * 2);
        int ti = (int)tf.x;
        float fr = __uint_as_float(tf.y);
        uint4 tq = ((const uint4*)tab4)[((size_t)ti << 5) + u];
        float4 x4 = *(const float4*)(xsv + (size_t)src * 128 + u * 4);
        float wa = bf2f_lo(tq.x) + fr * bf2f_lo(tq.z);
        float wc = bf2f_hi(tq.x) + fr * bf2f_hi(tq.z);
        float wb = bf2f_lo(tq.y) + fr * bf2f_lo(tq.w);
        float wd = bf2f_hi(tq.y) + fr * bf2f_hi(tq.w);
        as0 += wa * x4.w;
        as1 += wb * (vv.x * x4.x + vv.y * x4.y + vv.z * x4.z) * INV_SQRT3_F;
        float tt = wc * x4.w;
        av00 += tt * vv.x;  av01 += tt * vv.y;  av02 += tt * vv.z;
        av10 += wd * x4.x; av11 += wd * x4.y; av12 += wd * x4.z;
    };

    int i = quarter;
    for (; i + 4 < deg; i += 8) { body(o + i); body(o + i + 4); }
    for (; i < deg; i += 4) body(o + i);

    as0 += __shfl_down(as0, 32);  as1 += __shfl_down(as1, 32);
    av00 += __shfl_down(av00, 32); av01 += __shfl_down(av01, 32); av02 += __shfl_down(av02, 32);
    av10 += __shfl_down(av10, 32); av11 += __shfl_down(av11, 32); av12 += __shfl_down(av12, 32);

    int lane = threadIdx.x & 63;
    int upper_wave = (threadIdx.x >> 6) & 1;
    if (upper_wave && lane < 32) {
        red[pair][0][u] = as0;  red[pair][1][u] = as1;
        red[pair][2][u] = av00; red[pair][3][u] = av01; red[pair][4][u] = av02;
        red[pair][5][u] = av10; red[pair][6][u] = av11; red[pair][7][u] = av12;
    }
    __syncthreads();
    if (!upper_wave && lane < 32) {
        // final scaled agg vector -> red
        red[pair][0][u] = (as0 + red[pair][0][u]) * INV_SQRTNN_F;   // agg_s[u]
        red[pair][1][u] = (as1 + red[pair][1][u]) * INV_SQRTNN_F;   // agg_s[32+u]
        red[pair][2][u] = (av00 + red[pair][2][u]) * INV_SQRTNN_F;  // agg_v[u][.]
        red[pair][3][u] = (av01 + red[pair][3][u]) * INV_SQRTNN_F;
        red[pair][4][u] = (av02 + red[pair][4][u]) * INV_SQRTNN_F;
        red[pair][5][u] = (av10 + red[pair][5][u]) * INV_SQRTNN_F;  // agg_v[32+u][.]
        red[pair][6][u] = (av11 + red[pair][6][u]) * INV_SQRTNN_F;
        red[pair][7][u] = (av12 + red[pair][7][u]) * INV_SQRTNN_F;
    }
    __syncthreads();

    // ---- update phase: all 128 threads/node; quarter q covers uu in
    // [q*16,(q+1)*16); shfl+LDS reduce the 4 partials; lower-wave finalizes.
    {
        int half = quarter >> 1;            // uu<32 for q0,q1; uu>=32 for q2,q3
        int ub = (quarter & 1) * 16;        // within-half base
        int w = u;
        float4 at = {0.f, 0.f, 0.f, 0.f};
        if (active) at = *(const float4*)(attr + node * 4);
        const float* rs = red[pair][half];
        const float* r0 = red[pair][2 + 3 * half];
        const float* r1 = red[pair][3 + 3 * half];
        const float* r2 = red[pair][4 + 3 * half];
        float pacc = 0.f, pa0 = 0.f, pa1 = 0.f, pa2 = 0.f;
#pragma unroll
        for (int k = 0; k < 16; k++) {
            int j = ub + k;                 // index within half, 0..31
            float gs = rs[j], g0 = r0[j], g1 = r1[j], g2 = r2[j];
            uint4 pv = *(const uint4*)(Wupk + (half * 32 + j) * 128 + w * 4);
            float w20x = bf2f_lo(pv.x), w21x = bf2f_hi(pv.x);
            float w20y = bf2f_lo(pv.y), w21y = bf2f_hi(pv.y);
            float w20z = bf2f_lo(pv.z), w21z = bf2f_hi(pv.z);
            float w20w = bf2f_lo(pv.w), w21w = bf2f_hi(pv.w);
            float d0 = at.x * w20x + at.y * w20y + at.z * w20z + at.w * w20w;
            float d1 = at.x * w21x + at.y * w21y + at.z * w21z + at.w * w21w;
            pacc += gs * d0;
            pa0 += g0 * d1; pa1 += g1 * d1; pa2 += g2 * d1;
        }
        pacc += __shfl_down(pacc, 32);
        pa0 += __shfl_down(pa0, 32);
        pa1 += __shfl_down(pa1, 32);
        pa2 += __shfl_down(pa2, 32);
        if (upper_wave && lane < 32) {
            part[pair][0][u] = pacc;
            part[pair][1][u] = pa0;
            part[pair][2][u] = pa1;
            part[pair][3][u] = pa2;
        }
        __syncthreads();
        if (active && !upper_wave && lane < 32) {
            pacc += part[pair][0][u];
            pa0 += part[pair][1][u];
            pa1 += part[pair][2][u];
            pa2 += part[pair][3][u];
            float os = pacc * NORM256_F;
            float sn = C_S_F * sc_s[node * 32 + w] + C_X_F * os;
            float sig = 1.0f / (1.0f + __expf(-sn));
            s[node * 32 + w] += sn * sig;   // silu(sn)
            float ov0 = pa0 * NORM256_F, ov1 = pa1 * NORM256_F, ov2 = pa2 * NORM256_F;
            v[node * 96 + w * 3 + 0] += (C_S_F * sc_v[node * 96 + w * 3 + 0] + C_X_F * ov0) * sig;
            v[node * 96 + w * 3 + 1] += (C_S_F * sc_v[node * 96 + w * 3 + 1] + C_X_F * ov1) * sig;
            v[node * 96 + w * 3 + 2] += (C_S_F * sc_v[node * 96 + w * 3 + 2] + C_X_F * ov2) * sig;
        }
    }
}

// ---------------------------------------------------------------- readout
__global__ __launch_bounds__(256) void readout(
    const float* __restrict__ s, const float* __restrict__ attr,
    const float* __restrict__ Wread, const int* __restrict__ batch,
    float* __restrict__ out, int N, float pool_scale) {
    __shared__ float wr[2048];
    __shared__ float red[NGRAPH * 16];
    for (int i = threadIdx.x; i < 2048; i += 256) wr[i] = Wread[i];
    if (threadIdx.x < NGRAPH * 16) red[threadIdx.x] = 0.f;
    __syncthreads();
    int ln = threadIdx.x >> 4, w = threadIdx.x & 15;
    for (int g = 0; g < 4; g++) {
        int n = blockIdx.x * 64 + g * 16 + ln;
        if (n < N) {
            float4 at = *(const float4*)(attr + n * 4);
            float fa[4] = {at.x, at.y, at.z, at.w};
            float acc = 0.f;
            for (int u = 0; u < 32; u++) {
                float su = s[n * 32 + u];
                int base = u * 64 + w;
#pragma unroll
                for (int a = 0; a < 4; a++) acc += su * fa[a] * wr[base + a * 16];
            }
            atomicAdd(&red[batch[n] * 16 + w], acc);
        }
    }
    __syncthreads();
    if (threadIdx.x < NGRAPH * 16) {
        float val = red[threadIdx.x];
        if (val != 0.f)
            atomicAdd(&out[threadIdx.x], val * NORM128_F * pool_scale);
    }
}

// ---------------------------------------------------------------- launch
extern "C" void kernel_launch(void* const* d_in, const int* in_sizes, int n_in,
                              void* d_out, int out_size, void* d_ws, size_t ws_size,
                              hipStream_t stream) {
    const float* x        = (const float*)d_in[0];
    const float* nattr    = (const float*)d_in[1];
    const float* edge_vec = (const float*)d_in[2];
    const int*   batch    = (const int*)d_in[3];
    const int*   esrc     = (const int*)d_in[4];
    const int*   edst     = (const int*)d_in[5];
    const float* Wsc0  = (const float*)d_in[6];
    const float* Wsc1  = (const float*)d_in[7];
    const float* Wl10  = (const float*)d_in[8];
    const float* Wl11  = (const float*)d_in[9];
    const float* Wfc1  = (const float*)d_in[10];
    const float* Wfc2  = (const float*)d_in[11];
    const float* Wl20  = (const float*)d_in[12];
    const float* Wl21  = (const float*)d_in[13];
    const float* Wread = (const float*)d_in[14];

    int N = in_sizes[0] / (MUL * 4);
    int E = in_sizes[2] / 3;

    float* p = (float*)d_ws;
    float* vec_csr = p; p += (size_t)E * 4;     // {y0,y1,y2,src-bits}
    unsigned* tifr = (unsigned*)p; p += ((size_t)E * 2 + 3) & ~(size_t)3;  // {ti,fr}/slot
    unsigned* tab = (unsigned*)p; p += 2 * NT * 64;  // w(len) tables, packed bf16
    unsigned* tab4 = (unsigned*)p; p += 2 * 512 * 32 * 4;  // delta-form tables
    float* Wfp    = p; p += 32768;              // 2 layers x 4 matrices x 4096
    unsigned* Wupk = (unsigned*)p; p += 16384;  // 2 layers x 8192 packed pair dwords
    float* s_buf  = p; p += (size_t)N * 32;
    float* v_buf  = p; p += (size_t)N * 96;
    float* sc_s   = p; p += (size_t)N * 32;
    float* sc_v   = p; p += (size_t)N * 96;
    float* xsv    = p; p += (size_t)N * 128;    // {xv0,xv1,xv2,xs} per (n,u)
    int* cnt     = (int*)p; p += N;
    int* off     = (int*)p; p += N;
    int* cursor  = (int*)p; p += N;
    int* gcur    = (int*)p; p += 1;

    hipMemsetAsync(d_out, 0, (size_t)out_size * sizeof(float), stream);
    hipMemsetAsync(cnt, 0, ((size_t)3 * N + 1) * sizeof(int), stream);  // cnt..gcur

    int nTab   = (2 * NT + 3) / 4;              // 4 rows per block
    int nInit  = (N * 128 + 255) / 256;
    int nSetup = 192;
    int nCount = (E + 255) / 256;
    mega1<<<nTab + nInit + nSetup + nCount, 256, 0, stream>>>(
        nTab, nInit, nSetup, x, s_buf, v_buf,
        Wfc1, Wfc2, Wsc0, Wl10, Wsc1, Wl11, Wl20, Wl21,
        Wfp, Wupk, tab, edst, cnt, N, E);

    csr_alloc<<<(N + 255) / 256, 256, 0, stream>>>(cnt, off, cursor, gcur, N);

    int nFill = (E + 255) / 256;
    int nF = (N + 15) / 16;
    int nConv = (2 * 512 * 32 + 255) / 256;     // tab4 converter blocks
    mega2<<<nFill + 2 * nF + nConv, 256, 0, stream>>>(
        nFill, nF, edst, esrc, edge_vec, cursor, vec_csr, tifr, E,
        s_buf, v_buf, nattr, Wfp, sc_s, sc_v, xsv, N, tab, tab4);

    int nG = (N + 1) / 2;

    // ---- layer 0: gather+update fused, then next-layer fctp
    gather_update<<<nG, 256, 0, stream>>>(
        off, cnt, tab4, vec_csr, tifr, xsv, nattr, Wupk,
        sc_s, sc_v, s_buf, v_buf, N);
    fctp_only<<<2 * nF, 256, 0, stream>>>(
        nF, s_buf, v_buf, nattr, Wfp + 16384, sc_s, sc_v, xsv, N);

    // ---- layer 1: gather+update fused (no further fctp)
    gather_update<<<nG, 256, 0, stream>>>(
        off, cnt, tab4 + 512 * 32 * 4, vec_csr, tifr, xsv, nattr, Wupk + 8192,
        sc_s, sc_v, s_buf, v_buf, N);

    float pool_scale = (float)(1.0 / sqrt((double)N / (double)NGRAPH));
    readout<<<(N + 63) / 64, 256, 0, stream>>>(
        s_buf, nattr, Wread, batch, (float*)d_out, N, pool_scale);
}

// Round 16
// 252.123 us; speedup vs baseline: 1.2227x; 1.0216x over previous
//
#include <hip/hip_runtime.h>
#include <math.h>

#define MUL 32
#define NATTR 4
#define NBASIS 10
#define HID 64
#define OUT_DIM 16
#define NGRAPH 8
#define NT 513      // w(len) table entries: len = i/128, i in [0,512]

#define PI_F 3.14159265358979323846f
#define SQRT3_F 1.7320508075688772f
#define INV_SQRT10_F 0.31622776601683794f
#define INV_SQRTNN_F 0.17677669529663687f   // 1/sqrt(32)
#define NORM128_F 0.08838834764831845f      // 1/sqrt(128)
#define NORM256_F 0.0625f                   // 1/sqrt(256)
#define C_S_F 0.3826834323650898f           // sin(pi/8)
#define C_X_F 0.9238795325112867f           // cos(pi/8)
#define CSTEP_F (4.0f/9.0f)                 // linspace(0,4,10) step

__device__ inline unsigned short f2bf(float x) {
    unsigned u = __float_as_uint(x);
    u += 0x7FFF + ((u >> 16) & 1);          // round-to-nearest-even
    return (unsigned short)(u >> 16);
}
__device__ inline float bf2f(unsigned short h) {
    return __uint_as_float(((unsigned)h) << 16);
}
__device__ inline float bf2f_lo(unsigned x) {       // low bf16 of packed pair
    return __uint_as_float(x << 16);
}
__device__ inline float bf2f_hi(unsigned x) {       // high bf16 of packed pair
    return __uint_as_float(x & 0xFFFF0000u);
}

// ---------------------------------------------------------------- bodies
__device__ __forceinline__ void init_sv_body(
    int blk, const float* __restrict__ x,
    float* __restrict__ s, float* __restrict__ v, int N) {
    int i = blk * 256 + threadIdx.x;
    if (i >= N * 128) return;
    int n = i >> 7, c = i & 127;
    float val = x[i];
    if (c < 32) s[n * 32 + c] = val;
    else        v[n * 96 + (c - 32)] = val;
}

__device__ __forceinline__ void setup_weights_body(
    int blk,
    const float* __restrict__ Wsc0, const float* __restrict__ Wl10,
    const float* __restrict__ Wsc1, const float* __restrict__ Wl11,
    const float* __restrict__ Wl20, const float* __restrict__ Wl21,
    float* __restrict__ Wfp, unsigned* __restrict__ Wupk) {
    int i = blk * 256 + threadIdx.x;
    if (i < 32768) {
        int idx = i >> 12;          // l*4 + m
        int r = i & 4095;
        int l = idx >> 2, m = idx & 3;
        const float* base = (m == 0 ? Wsc0 : m == 1 ? Wl10 : m == 2 ? Wsc1 : Wl11)
                            + l * 4096;
        int u = r >> 7, rr = r & 127, a = rr >> 5, ww = rr & 31;
        Wfp[idx * 4096 + u * 128 + ww * 4 + a] = base[r];
    } else if (i < 49152) {
        int j = i - 32768;
        int l = j >> 13;
        int r = j & 8191;
        int u = r >> 7, rr = r & 127, a = rr >> 5, ww = rr & 31;
        unsigned lo = f2bf(Wl20[l * 8192 + r]);
        unsigned hi = f2bf(Wl21[l * 8192 + r]);
        Wupk[l * 8192 + u * 128 + ww * 4 + a] = lo | (hi << 16);
    }
}

// w(len) table generator, cooperative: one 64-thread group per table row.
__device__ __forceinline__ void tab_gen_body(
    int blk, const float* __restrict__ Wfc1, const float* __restrict__ Wfc2,
    unsigned* __restrict__ tab, float (*sh_h)[64]) {
    int g = threadIdx.x >> 6;       // row group 0..3
    int n = threadIdx.x & 63;       // h index / output j
    int row = blk * 4 + g;
    bool valid = row < 2 * NT;
    int l = valid ? row / NT : 0;
    int i = valid ? row % NT : 0;
    float len = (float)i * (1.0f / 128.0f);
    float uu = len * 0.5f - 2.0f;
    float cut = (uu > 0.0f) ? 0.0f
              : ((uu < -1.0f) ? 1.0f : 0.5f * (1.0f - __cosf(PI_F * uu)));
    const float* W1 = Wfc1 + l * 640;
    float a = 0.f;
#pragma unroll
    for (int k = 0; k < 10; k++) {
        float d = (len - k * CSTEP_F) * 2.5f;
        float e = __expf(-d * d) * cut;
        a += e * W1[k * 64 + n];
    }
    a *= INV_SQRT10_F;
    sh_h[g][n] = a / (1.0f + __expf(-a));
    __syncthreads();
    if (!valid) return;
    const float* W2 = Wfc2 + l * 8192;
    float w0 = 0.f, w1 = 0.f;
#pragma unroll 8
    for (int nn = 0; nn < 64; nn++) {
        float hn = sh_h[g][nn];
        w0 += hn * W2[nn * 128 + n];
        w1 += hn * W2[nn * 128 + 64 + n];
    }
    w0 *= 0.125f; w1 *= 0.125f;
    tab[(size_t)l * NT * 64 + i * 64 + n] =
        (unsigned)f2bf(w0) | ((unsigned)f2bf(w1) << 16);
}

// tab4 converter: tab4[l][ti][u] (uint4, ti in [0,512), u in [0,32)) =
// { pk(w0, sqrt3*w2)@ti, pk(w1,w3)@ti, pk(deltas of col0), pk(deltas of col1) }
// The sqrt3 fold lets the gather store UNIT edge vectors (y = sqrt3*unit
// becomes implicit) and drops the 1/sqrt3 multiply from the s-channel.
__device__ __forceinline__ void tab4_body(
    int blk, const unsigned* __restrict__ tab, unsigned* __restrict__ tab4) {
    int id = blk * 256 + threadIdx.x;
    if (id >= 2 * 512 * 32) return;
    int l = id >> 14;
    int r = id & 16383;
    int ti = r >> 5, u = r & 31;
    const unsigned* tb = tab + (size_t)l * NT * 64 + ti * 64;
    unsigned a0 = tb[u],      a1 = tb[u + 32];
    unsigned b0 = tb[64 + u], b1 = tb[64 + u + 32];
    float a0l = bf2f((unsigned short)a0), a0h = SQRT3_F * bf2f((unsigned short)(a0 >> 16));
    float b0l = bf2f((unsigned short)b0), b0h = SQRT3_F * bf2f((unsigned short)(b0 >> 16));
    float d0l = b0l - a0l, d0h = b0h - a0h;
    float d1l = bf2f((unsigned short)b1) - bf2f((unsigned short)a1);
    float d1h = bf2f((unsigned short)(b1 >> 16)) - bf2f((unsigned short)(a1 >> 16));
    uint4 q;
    q.x = (unsigned)f2bf(a0l) | ((unsigned)f2bf(a0h) << 16);
    q.y = a1;
    q.z = (unsigned)f2bf(d0l) | ((unsigned)f2bf(d0h) << 16);
    q.w = (unsigned)f2bf(d1l) | ((unsigned)f2bf(d1h) << 16);
    ((uint4*)tab4)[((size_t)l * 512 + ti) * 32 + u] = q;
}

__device__ __forceinline__ void csr_count_body(
    int blk, const int* __restrict__ edst, int* __restrict__ cnt, int E) {
    int e = blk * 256 + threadIdx.x;
    if (e < E) atomicAdd(&cnt[edst[e]], 1);
}

// csr_fill: store UNIT vector + src; pack {ti, fr16} into one dword per slot.
__device__ __forceinline__ void csr_fill_body(
    int blk, const int* __restrict__ edst, const int* __restrict__ esrc,
    const float* __restrict__ edge_vec, int* __restrict__ cursor,
    float* __restrict__ vec_csr, unsigned* __restrict__ tifr, int E) {
    int e = blk * 256 + threadIdx.x;
    if (e < E) {
        int d = edst[e];
        int p = atomicAdd(&cursor[d], 1);
        float ex = edge_vec[e * 3 + 0], ey = edge_vec[e * 3 + 1], ez = edge_vec[e * 3 + 2];
        float len = sqrtf(ex * ex + ey * ey + ez * ez);
        float rinv = 1.0f / (len + 1e-9f);
        float t = fminf(len, 3.99995f) * 128.0f;
        int ti = (int)t;
        float fr = t - (float)ti;
        unsigned fr16 = (unsigned)(fr * 65536.0f);
        if (fr16 > 65535u) fr16 = 65535u;
        float4 vv = {ex * rinv, ey * rinv, ez * rinv, __int_as_float(esrc[e])};
        *(float4*)(vec_csr + (size_t)p * 4) = vv;
        tifr[p] = (unsigned)ti | (fr16 << 16);
    }
}

// node fctp: 16 nodes/block; smem: [0,16K) w0 | [16K,32K) w1 | [32K,35K) sh
__device__ __forceinline__ void node_fctp_body(
    int blk, int path,
    const float* __restrict__ s, const float* __restrict__ v,
    const float* __restrict__ attr, const float* __restrict__ Wfp,
    float* __restrict__ sc_s, float* __restrict__ sc_v,
    float* __restrict__ xsv, int N, char* smem) {
    float* w0 = (float*)smem;
    float* w1 = (float*)(smem + 16384);
    float (*sh)[96] = (float(*)[96])(smem + 32768);
    int ln = threadIdx.x >> 5, w = threadIdx.x & 31;
    const float4* W0p = (const float4*)(Wfp + path * 8192);
    const float4* W1p = (const float4*)(Wfp + path * 8192 + 4096);
    for (int i = threadIdx.x; i < 1024; i += 256) {
        ((float4*)w0)[i] = W0p[i];
        ((float4*)w1)[i] = W1p[i];
    }
    for (int g = 0; g < 2; g++) {
        int n = blk * 16 + g * 8 + ln;
        bool valid = n < N;
        __syncthreads();
        if (valid) {
            if (path == 0) {
                sh[ln][w] = s[n * 32 + w];
            } else {
                sh[ln][w * 3 + 0] = v[n * 96 + w * 3 + 0];
                sh[ln][w * 3 + 1] = v[n * 96 + w * 3 + 1];
                sh[ln][w * 3 + 2] = v[n * 96 + w * 3 + 2];
            }
        }
        __syncthreads();
        if (!valid) continue;
        float4 at = *(const float4*)(attr + n * 4);
        if (path == 0) {
            float acc0 = 0.f, acc1 = 0.f;
            for (int u = 0; u < 32; u++) {
                float su = sh[ln][u];
                float4 W0v = *(const float4*)(w0 + u * 128 + w * 4);
                float4 W1v = *(const float4*)(w1 + u * 128 + w * 4);
                float d0 = at.x * W0v.x + at.y * W0v.y + at.z * W0v.z + at.w * W0v.w;
                float d1 = at.x * W1v.x + at.y * W1v.y + at.z * W1v.z + at.w * W1v.w;
                acc0 += su * d0;
                acc1 += su * d1;
            }
            sc_s[n * 32 + w] = acc0 * NORM128_F;
            xsv[(size_t)n * 128 + w * 4 + 3] = acc1 * NORM128_F;
        } else {
            float a00 = 0, a01 = 0, a02 = 0, a10 = 0, a11 = 0, a12 = 0;
            for (int u = 0; u < 32; u++) {
                float vu0 = sh[ln][u * 3 + 0];
                float vu1 = sh[ln][u * 3 + 1];
                float vu2 = sh[ln][u * 3 + 2];
                float4 W0v = *(const float4*)(w0 + u * 128 + w * 4);
                float4 W1v = *(const float4*)(w1 + u * 128 + w * 4);
                float d0 = at.x * W0v.x + at.y * W0v.y + at.z * W0v.z + at.w * W0v.w;
                float d1 = at.x * W1v.x + at.y * W1v.y + at.z * W1v.z + at.w * W1v.w;
                a00 += vu0 * d0; a01 += vu1 * d0; a02 += vu2 * d0;
                a10 += vu0 * d1; a11 += vu1 * d1; a12 += vu2 * d1;
            }
            sc_v[n * 96 + w * 3 + 0] = a00 * NORM128_F;
            sc_v[n * 96 + w * 3 + 1] = a01 * NORM128_F;
            sc_v[n * 96 + w * 3 + 2] = a02 * NORM128_F;
            float* xp = xsv + (size_t)n * 128 + w * 4;
            xp[0] = a10 * NORM128_F;
            xp[1] = a11 * NORM128_F;
            xp[2] = a12 * NORM128_F;
        }
    }
}

// ---------------------------------------------------------------- mega kernels
// tab blocks FIRST so the table generation starts immediately.
__global__ __launch_bounds__(256) void mega1(
    int nTab, int nInit, int nSetup,
    const float* __restrict__ x, float* __restrict__ s, float* __restrict__ v,
    const float* __restrict__ Wfc1, const float* __restrict__ Wfc2,
    const float* __restrict__ Wsc0, const float* __restrict__ Wl10,
    const float* __restrict__ Wsc1, const float* __restrict__ Wl11,
    const float* __restrict__ Wl20, const float* __restrict__ Wl21,
    float* __restrict__ Wfp, unsigned* __restrict__ Wupk,
    unsigned* __restrict__ tab,
    const int* __restrict__ edst, int* __restrict__ cnt, int N, int E) {
    __shared__ float sh_h[4][64];
    int b = blockIdx.x;
    if (b < nTab) { tab_gen_body(b, Wfc1, Wfc2, tab, sh_h); return; }
    b -= nTab;
    if (b < nInit) { init_sv_body(b, x, s, v, N); return; }
    b -= nInit;
    if (b < nSetup) {
        setup_weights_body(b, Wsc0, Wl10, Wsc1, Wl11, Wl20, Wl21, Wfp, Wupk);
        return;
    }
    b -= nSetup;
    csr_count_body(b, edst, cnt, E);
}

// Parallel CSR slot allocation: per-wave64 inclusive shfl-scan of cnt, one
// atomicAdd per wave for the base. Slot order across waves is arbitrary —
// every consumer is order-independent (per-node sums).
__global__ __launch_bounds__(256) void csr_alloc(
    const int* __restrict__ cnt, int* __restrict__ off,
    int* __restrict__ cursor, int* __restrict__ gcur, int N) {
    int i = blockIdx.x * 256 + threadIdx.x;
    int lane = threadIdx.x & 63;
    int c = (i < N) ? cnt[i] : 0;
    int sc = c;
#pragma unroll
    for (int d = 1; d < 64; d <<= 1) {
        int t = __shfl_up(sc, d);
        if (lane >= d) sc += t;
    }
    int total = __shfl(sc, 63);
    int base = 0;
    if (lane == 0) base = atomicAdd(gcur, total);
    base = __shfl(base, 0);
    if (i < N) {
        int o = base + sc - c;      // exclusive position
        off[i] = o;
        cursor[i] = o;
    }
}

// csr_fill || fctp(layer0, both paths) || tab4 conversion
__global__ __launch_bounds__(256, 4) void mega2(
    int nFill, int nF,
    const int* __restrict__ edst, const int* __restrict__ esrc,
    const float* __restrict__ edge_vec, int* __restrict__ cursor,
    float* __restrict__ vec_csr, unsigned* __restrict__ tifr, int E,
    const float* __restrict__ s, const float* __restrict__ v,
    const float* __restrict__ attr, const float* __restrict__ Wfp,
    float* __restrict__ sc_s, float* __restrict__ sc_v,
    float* __restrict__ xsv, int N,
    const unsigned* __restrict__ tab, unsigned* __restrict__ tab4) {
    __shared__ __align__(16) char smem[35840];
    int b = blockIdx.x;
    if (b < nFill) {
        csr_fill_body(b, edst, esrc, edge_vec, cursor, vec_csr, tifr, E);
        return;
    }
    b -= nFill;
    if (b < 2 * nF) {
        node_fctp_body(b % nF, b / nF, s, v, attr, Wfp, sc_s, sc_v, xsv, N, smem);
        return;
    }
    b -= 2 * nF;
    tab4_body(b, tab, tab4);
}

// next-layer fctp (both paths) as a standalone dispatch
__global__ __launch_bounds__(256, 4) void fctp_only(
    int nF,
    const float* __restrict__ s, const float* __restrict__ v,
    const float* __restrict__ attr, const float* __restrict__ Wfp,
    float* __restrict__ sc_s, float* __restrict__ sc_v,
    float* __restrict__ xsv, int N) {
    __shared__ __align__(16) char smem[35840];
    node_fctp_body(blockIdx.x % nF, blockIdx.x / nF, s, v, attr, Wfp,
                   sc_s, sc_v, xsv, N, smem);
}

// ---------------------------------------------------------------- gather+update
// 2 nodes/block, 128 threads each (4 quarter-waves striding slots by 4).
// Edge weights from the delta-form tab4 (sqrt3 pre-folded into w2 column;
// vec_csr holds the UNIT edge vector); ti/fr packed into one dword per slot.
// Agg stays in LDS; update phase runs wave-parallel. No atomics anywhere.
__global__ __launch_bounds__(256, 4) void gather_update(
    const int* __restrict__ off, const int* __restrict__ cnt,
    const unsigned* __restrict__ tab4,
    const float* __restrict__ vec_csr, const unsigned* __restrict__ tifr,
    const float* __restrict__ xsv,
    const float* __restrict__ attr, const unsigned* __restrict__ Wupk,
    const float* __restrict__ sc_s, const float* __restrict__ sc_v,
    float* __restrict__ s, float* __restrict__ v, int N) {
    __shared__ float red[2][8][32];
    __shared__ float part[2][4][32];
    int pair = threadIdx.x >> 7;
    int node = blockIdx.x * 2 + pair;
    int ql = threadIdx.x & 127;
    int quarter = ql >> 5;
    int u = ql & 31;
    bool active = node < N;
    int o = 0, deg = 0;
    if (active) { o = off[node]; deg = cnt[node]; }
    float as0 = 0, as1 = 0;
    float av00 = 0, av01 = 0, av02 = 0, av10 = 0, av11 = 0, av12 = 0;

    auto body = [&](int slot) {
        size_t p = (size_t)slot;
        float4 vv = *(const float4*)(vec_csr + p * 4);   // unit0..2, src
        int src = __float_as_int(vv.w);
        unsigned tf = tifr[p];
        int ti = (int)(tf & 0xFFFFu);
        float fr = (float)(tf >> 16) * (1.0f / 65536.0f);
        uint4 tq = ((const uint4*)tab4)[((size_t)ti << 5) + u];
        float4 x4 = *(const float4*)(xsv + (size_t)src * 128 + u * 4);
        float wa = bf2f_lo(tq.x) + fr * bf2f_lo(tq.z);   // w0
        float wc = bf2f_hi(tq.x) + fr * bf2f_hi(tq.z);   // sqrt3*w2
        float wb = bf2f_lo(tq.y) + fr * bf2f_lo(tq.w);   // w1
        float wd = bf2f_hi(tq.y) + fr * bf2f_hi(tq.w);   // w3
        as0 += wa * x4.w;
        as1 += wb * (vv.x * x4.x + vv.y * x4.y + vv.z * x4.z);
        float tt = wc * x4.w;
        av00 += tt * vv.x;  av01 += tt * vv.y;  av02 += tt * vv.z;
        av10 += wd * x4.x; av11 += wd * x4.y; av12 += wd * x4.z;
    };

    int i = quarter;
    for (; i + 4 < deg; i += 8) { body(o + i); body(o + i + 4); }
    for (; i < deg; i += 4) body(o + i);

    as0 += __shfl_down(as0, 32);  as1 += __shfl_down(as1, 32);
    av00 += __shfl_down(av00, 32); av01 += __shfl_down(av01, 32); av02 += __shfl_down(av02, 32);
    av10 += __shfl_down(av10, 32); av11 += __shfl_down(av11, 32); av12 += __shfl_down(av12, 32);

    int lane = threadIdx.x & 63;
    int upper_wave = (threadIdx.x >> 6) & 1;
    if (upper_wave && lane < 32) {
        red[pair][0][u] = as0;  red[pair][1][u] = as1;
        red[pair][2][u] = av00; red[pair][3][u] = av01; red[pair][4][u] = av02;
        red[pair][5][u] = av10; red[pair][6][u] = av11; red[pair][7][u] = av12;
    }
    __syncthreads();
    if (!upper_wave && lane < 32) {
        // final scaled agg vector -> red
        red[pair][0][u] = (as0 + red[pair][0][u]) * INV_SQRTNN_F;   // agg_s[u]
        red[pair][1][u] = (as1 + red[pair][1][u]) * INV_SQRTNN_F;   // agg_s[32+u]
        red[pair][2][u] = (av00 + red[pair][2][u]) * INV_SQRTNN_F;  // agg_v[u][.]
        red[pair][3][u] = (av01 + red[pair][3][u]) * INV_SQRTNN_F;
        red[pair][4][u] = (av02 + red[pair][4][u]) * INV_SQRTNN_F;
        red[pair][5][u] = (av10 + red[pair][5][u]) * INV_SQRTNN_F;  // agg_v[32+u][.]
        red[pair][6][u] = (av11 + red[pair][6][u]) * INV_SQRTNN_F;
        red[pair][7][u] = (av12 + red[pair][7][u]) * INV_SQRTNN_F;
    }
    __syncthreads();

    // ---- update phase: all 128 threads/node; quarter q covers uu in
    // [q*16,(q+1)*16); shfl+LDS reduce the 4 partials; lower-wave finalizes.
    {
        int half = quarter >> 1;            // uu<32 for q0,q1; uu>=32 for q2,q3
        int ub = (quarter & 1) * 16;        // within-half base
        int w = u;
        float4 at = {0.f, 0.f, 0.f, 0.f};
        if (active) at = *(const float4*)(attr + node * 4);
        const float* rs = red[pair][half];
        const float* r0 = red[pair][2 + 3 * half];
        const float* r1 = red[pair][3 + 3 * half];
        const float* r2 = red[pair][4 + 3 * half];
        float pacc = 0.f, pa0 = 0.f, pa1 = 0.f, pa2 = 0.f;
#pragma unroll
        for (int k = 0; k < 16; k++) {
            int j = ub + k;                 // index within half, 0..31
            float gs = rs[j], g0 = r0[j], g1 = r1[j], g2 = r2[j];
            uint4 pv = *(const uint4*)(Wupk + (half * 32 + j) * 128 + w * 4);
            float w20x = bf2f_lo(pv.x), w21x = bf2f_hi(pv.x);
            float w20y = bf2f_lo(pv.y), w21y = bf2f_hi(pv.y);
            float w20z = bf2f_lo(pv.z), w21z = bf2f_hi(pv.z);
            float w20w = bf2f_lo(pv.w), w21w = bf2f_hi(pv.w);
            float d0 = at.x * w20x + at.y * w20y + at.z * w20z + at.w * w20w;
            float d1 = at.x * w21x + at.y * w21y + at.z * w21z + at.w * w21w;
            pacc += gs * d0;
            pa0 += g0 * d1; pa1 += g1 * d1; pa2 += g2 * d1;
        }
        pacc += __shfl_down(pacc, 32);
        pa0 += __shfl_down(pa0, 32);
        pa1 += __shfl_down(pa1, 32);
        pa2 += __shfl_down(pa2, 32);
        if (upper_wave && lane < 32) {
            part[pair][0][u] = pacc;
            part[pair][1][u] = pa0;
            part[pair][2][u] = pa1;
            part[pair][3][u] = pa2;
        }
        __syncthreads();
        if (active && !upper_wave && lane < 32) {
            pacc += part[pair][0][u];
            pa0 += part[pair][1][u];
            pa1 += part[pair][2][u];
            pa2 += part[pair][3][u];
            float os = pacc * NORM256_F;
            float sn = C_S_F * sc_s[node * 32 + w] + C_X_F * os;
            float sig = 1.0f / (1.0f + __expf(-sn));
            s[node * 32 + w] += sn * sig;   // silu(sn)
            float ov0 = pa0 * NORM256_F, ov1 = pa1 * NORM256_F, ov2 = pa2 * NORM256_F;
            v[node * 96 + w * 3 + 0] += (C_S_F * sc_v[node * 96 + w * 3 + 0] + C_X_F * ov0) * sig;
            v[node * 96 + w * 3 + 1] += (C_S_F * sc_v[node * 96 + w * 3 + 1] + C_X_F * ov1) * sig;
            v[node * 96 + w * 3 + 2] += (C_S_F * sc_v[node * 96 + w * 3 + 2] + C_X_F * ov2) * sig;
        }
    }
}

// ---------------------------------------------------------------- readout
__global__ __launch_bounds__(256) void readout(
    const float* __restrict__ s, const float* __restrict__ attr,
    const float* __restrict__ Wread, const int* __restrict__ batch,
    float* __restrict__ out, int N, float pool_scale) {
    __shared__ float wr[2048];
    __shared__ float red[NGRAPH * 16];
    for (int i = threadIdx.x; i < 2048; i += 256) wr[i] = Wread[i];
    if (threadIdx.x < NGRAPH * 16) red[threadIdx.x] = 0.f;
    __syncthreads();
    int ln = threadIdx.x >> 4, w = threadIdx.x & 15;
    for (int g = 0; g < 4; g++) {
        int n = blockIdx.x * 64 + g * 16 + ln;
        if (n < N) {
            float4 at = *(const float4*)(attr + n * 4);
            float fa[4] = {at.x, at.y, at.z, at.w};
            float acc = 0.f;
            for (int u = 0; u < 32; u++) {
                float su = s[n * 32 + u];
                int base = u * 64 + w;
#pragma unroll
                for (int a = 0; a < 4; a++) acc += su * fa[a] * wr[base + a * 16];
            }
            atomicAdd(&red[batch[n] * 16 + w], acc);
        }
    }
    __syncthreads();
    if (threadIdx.x < NGRAPH * 16) {
        float val = red[threadIdx.x];
        if (val != 0.f)
            atomicAdd(&out[threadIdx.x], val * NORM128_F * pool_scale);
    }
}

// ---------------------------------------------------------------- launch
extern "C" void kernel_launch(void* const* d_in, const int* in_sizes, int n_in,
                              void* d_out, int out_size, void* d_ws, size_t ws_size,
                              hipStream_t stream) {
    const float* x        = (const float*)d_in[0];
    const float* nattr    = (const float*)d_in[1];
    const float* edge_vec = (const float*)d_in[2];
    const int*   batch    = (const int*)d_in[3];
    const int*   esrc     = (const int*)d_in[4];
    const int*   edst     = (const int*)d_in[5];
    const float* Wsc0  = (const float*)d_in[6];
    const float* Wsc1  = (const float*)d_in[7];
    const float* Wl10  = (const float*)d_in[8];
    const float* Wl11  = (const float*)d_in[9];
    const float* Wfc1  = (const float*)d_in[10];
    const float* Wfc2  = (const float*)d_in[11];
    const float* Wl20  = (const float*)d_in[12];
    const float* Wl21  = (const float*)d_in[13];
    const float* Wread = (const float*)d_in[14];

    int N = in_sizes[0] / (MUL * 4);
    int E = in_sizes[2] / 3;

    float* p = (float*)d_ws;
    float* vec_csr = p; p += (size_t)E * 4;     // {unit0,unit1,unit2,src-bits}
    unsigned* tifr = (unsigned*)p; p += ((size_t)E + 3) & ~(size_t)3;  // {ti|fr16}/slot
    unsigned* tab = (unsigned*)p; p += 2 * NT * 64;  // w(len) tables, packed bf16
    unsigned* tab4 = (unsigned*)p; p += 2 * 512 * 32 * 4;  // delta-form tables
    float* Wfp    = p; p += 32768;              // 2 layers x 4 matrices x 4096
    unsigned* Wupk = (unsigned*)p; p += 16384;  // 2 layers x 8192 packed pair dwords
    float* s_buf  = p; p += (size_t)N * 32;
    float* v_buf  = p; p += (size_t)N * 96;
    float* sc_s   = p; p += (size_t)N * 32;
    float* sc_v   = p; p += (size_t)N * 96;
    float* xsv    = p; p += (size_t)N * 128;    // {xv0,xv1,xv2,xs} per (n,u)
    int* cnt     = (int*)p; p += N;
    int* off     = (int*)p; p += N;
    int* cursor  = (int*)p; p += N;
    int* gcur    = (int*)p; p += 1;

    hipMemsetAsync(d_out, 0, (size_t)out_size * sizeof(float), stream);
    hipMemsetAsync(cnt, 0, ((size_t)3 * N + 1) * sizeof(int), stream);  // cnt..gcur

    int nTab   = (2 * NT + 3) / 4;              // 4 rows per block
    int nInit  = (N * 128 + 255) / 256;
    int nSetup = 192;
    int nCount = (E + 255) / 256;
    mega1<<<nTab + nInit + nSetup + nCount, 256, 0, stream>>>(
        nTab, nInit, nSetup, x, s_buf, v_buf,
        Wfc1, Wfc2, Wsc0, Wl10, Wsc1, Wl11, Wl20, Wl21,
        Wfp, Wupk, tab, edst, cnt, N, E);

    csr_alloc<<<(N + 255) / 256, 256, 0, stream>>>(cnt, off, cursor, gcur, N);

    int nFill = (E + 255) / 256;
    int nF = (N + 15) / 16;
    int nConv = (2 * 512 * 32 + 255) / 256;     // tab4 converter blocks
    mega2<<<nFill + 2 * nF + nConv, 256, 0, stream>>>(
        nFill, nF, edst, esrc, edge_vec, cursor, vec_csr, tifr, E,
        s_buf, v_buf, nattr, Wfp, sc_s, sc_v, xsv, N, tab, tab4);

    int nG = (N + 1) / 2;

    // ---- layer 0: gather+update fused, then next-layer fctp
    gather_update<<<nG, 256, 0, stream>>>(
        off, cnt, tab4, vec_csr, tifr, xsv, nattr, Wupk,
        sc_s, sc_v, s_buf, v_buf, N);
    fctp_only<<<2 * nF, 256, 0, stream>>>(
        nF, s_buf, v_buf, nattr, Wfp + 16384, sc_s, sc_v, xsv, N);

    // ---- layer 1: gather+update fused (no further fctp)
    gather_update<<<nG, 256, 0, stream>>>(
        off, cnt, tab4 + 512 * 32 * 4, vec_csr, tifr, xsv, nattr, Wupk + 8192,
        sc_s, sc_v, s_buf, v_buf, N);

    float pool_scale = (float)(1.0 / sqrt((double)N / (double)NGRAPH));
    readout<<<(N + 63) / 64, 256, 0, stream>>>(
        s_buf, nattr, Wread, batch, (float*)d_out, N, pool_scale);
}

// Round 17
// 251.632 us; speedup vs baseline: 1.2250x; 1.0019x over previous
//
#include <hip/hip_runtime.h>
#include <math.h>

#define MUL 32
#define NATTR 4
#define NBASIS 10
#define HID 64
#define OUT_DIM 16
#define NGRAPH 8
#define NT 513      // w(len) table entries: len = i/128, i in [0,512]

#define PI_F 3.14159265358979323846f
#define SQRT3_F 1.7320508075688772f
#define INV_SQRT10_F 0.31622776601683794f
#define INV_SQRTNN_F 0.17677669529663687f   // 1/sqrt(32)
#define NORM128_F 0.08838834764831845f      // 1/sqrt(128)
#define NORM256_F 0.0625f                   // 1/sqrt(256)
#define C_S_F 0.3826834323650898f           // sin(pi/8)
#define C_X_F 0.9238795325112867f           // cos(pi/8)
#define CSTEP_F (4.0f/9.0f)                 // linspace(0,4,10) step

__device__ inline unsigned short f2bf(float x) {
    unsigned u = __float_as_uint(x);
    u += 0x7FFF + ((u >> 16) & 1);          // round-to-nearest-even
    return (unsigned short)(u >> 16);
}
__device__ inline float bf2f(unsigned short h) {
    return __uint_as_float(((unsigned)h) << 16);
}
__device__ inline float bf2f_lo(unsigned x) {       // low bf16 of packed pair
    return __uint_as_float(x << 16);
}
__device__ inline float bf2f_hi(unsigned x) {       // high bf16 of packed pair
    return __uint_as_float(x & 0xFFFF0000u);
}

// ---------------------------------------------------------------- bodies
__device__ __forceinline__ void init_sv_body(
    int blk, const float* __restrict__ x,
    float* __restrict__ s, float* __restrict__ v, int N) {
    int i = blk * 256 + threadIdx.x;
    if (i >= N * 128) return;
    int n = i >> 7, c = i & 127;
    float val = x[i];
    if (c < 32) s[n * 32 + c] = val;
    else        v[n * 96 + (c - 32)] = val;
}

__device__ __forceinline__ void setup_weights_body(
    int blk,
    const float* __restrict__ Wsc0, const float* __restrict__ Wl10,
    const float* __restrict__ Wsc1, const float* __restrict__ Wl11,
    const float* __restrict__ Wl20, const float* __restrict__ Wl21,
    float* __restrict__ Wfp, unsigned* __restrict__ Wupk) {
    int i = blk * 256 + threadIdx.x;
    if (i < 32768) {
        int idx = i >> 12;          // l*4 + m
        int r = i & 4095;
        int l = idx >> 2, m = idx & 3;
        const float* base = (m == 0 ? Wsc0 : m == 1 ? Wl10 : m == 2 ? Wsc1 : Wl11)
                            + l * 4096;
        int u = r >> 7, rr = r & 127, a = rr >> 5, ww = rr & 31;
        Wfp[idx * 4096 + u * 128 + ww * 4 + a] = base[r];
    } else if (i < 49152) {
        int j = i - 32768;
        int l = j >> 13;
        int r = j & 8191;
        int u = r >> 7, rr = r & 127, a = rr >> 5, ww = rr & 31;
        unsigned lo = f2bf(Wl20[l * 8192 + r]);
        unsigned hi = f2bf(Wl21[l * 8192 + r]);
        Wupk[l * 8192 + u * 128 + ww * 4 + a] = lo | (hi << 16);
    }
}

// w(len) table generator, cooperative: one 64-thread group per table row.
__device__ __forceinline__ void tab_gen_body(
    int blk, const float* __restrict__ Wfc1, const float* __restrict__ Wfc2,
    unsigned* __restrict__ tab, float (*sh_h)[64]) {
    int g = threadIdx.x >> 6;       // row group 0..3
    int n = threadIdx.x & 63;       // h index / output j
    int row = blk * 4 + g;
    bool valid = row < 2 * NT;
    int l = valid ? row / NT : 0;
    int i = valid ? row % NT : 0;
    float len = (float)i * (1.0f / 128.0f);
    float uu = len * 0.5f - 2.0f;
    float cut = (uu > 0.0f) ? 0.0f
              : ((uu < -1.0f) ? 1.0f : 0.5f * (1.0f - __cosf(PI_F * uu)));
    const float* W1 = Wfc1 + l * 640;
    float a = 0.f;
#pragma unroll
    for (int k = 0; k < 10; k++) {
        float d = (len - k * CSTEP_F) * 2.5f;
        float e = __expf(-d * d) * cut;
        a += e * W1[k * 64 + n];
    }
    a *= INV_SQRT10_F;
    sh_h[g][n] = a / (1.0f + __expf(-a));
    __syncthreads();
    if (!valid) return;
    const float* W2 = Wfc2 + l * 8192;
    float w0 = 0.f, w1 = 0.f;
#pragma unroll 8
    for (int nn = 0; nn < 64; nn++) {
        float hn = sh_h[g][nn];
        w0 += hn * W2[nn * 128 + n];
        w1 += hn * W2[nn * 128 + 64 + n];
    }
    w0 *= 0.125f; w1 *= 0.125f;
    tab[(size_t)l * NT * 64 + i * 64 + n] =
        (unsigned)f2bf(w0) | ((unsigned)f2bf(w1) << 16);
}

// tab4 converter: tab4[l][ti][u] (uint4, ti in [0,512), u in [0,32)) =
// { pk(w0, sqrt3*w2)@ti, pk(w1,w3)@ti, pk(deltas of col0), pk(deltas of col1) }
__device__ __forceinline__ void tab4_body(
    int blk, const unsigned* __restrict__ tab, unsigned* __restrict__ tab4) {
    int id = blk * 256 + threadIdx.x;
    if (id >= 2 * 512 * 32) return;
    int l = id >> 14;
    int r = id & 16383;
    int ti = r >> 5, u = r & 31;
    const unsigned* tb = tab + (size_t)l * NT * 64 + ti * 64;
    unsigned a0 = tb[u],      a1 = tb[u + 32];
    unsigned b0 = tb[64 + u], b1 = tb[64 + u + 32];
    float a0l = bf2f((unsigned short)a0), a0h = SQRT3_F * bf2f((unsigned short)(a0 >> 16));
    float b0l = bf2f((unsigned short)b0), b0h = SQRT3_F * bf2f((unsigned short)(b0 >> 16));
    float d0l = b0l - a0l, d0h = b0h - a0h;
    float d1l = bf2f((unsigned short)b1) - bf2f((unsigned short)a1);
    float d1h = bf2f((unsigned short)(b1 >> 16)) - bf2f((unsigned short)(a1 >> 16));
    uint4 q;
    q.x = (unsigned)f2bf(a0l) | ((unsigned)f2bf(a0h) << 16);
    q.y = a1;
    q.z = (unsigned)f2bf(d0l) | ((unsigned)f2bf(d0h) << 16);
    q.w = (unsigned)f2bf(d1l) | ((unsigned)f2bf(d1h) << 16);
    ((uint4*)tab4)[((size_t)l * 512 + ti) * 32 + u] = q;
}

__device__ __forceinline__ void csr_count_body(
    int blk, const int* __restrict__ edst, int* __restrict__ cnt, int E) {
    int e = blk * 256 + threadIdx.x;
    if (e < E) atomicAdd(&cnt[edst[e]], 1);
}

// csr_fill: store UNIT vector + src; pack {ti, fr16} into one dword per slot.
__device__ __forceinline__ void csr_fill_body(
    int blk, const int* __restrict__ edst, const int* __restrict__ esrc,
    const float* __restrict__ edge_vec, int* __restrict__ cursor,
    float* __restrict__ vec_csr, unsigned* __restrict__ tifr, int E) {
    int e = blk * 256 + threadIdx.x;
    if (e < E) {
        int d = edst[e];
        int p = atomicAdd(&cursor[d], 1);
        float ex = edge_vec[e * 3 + 0], ey = edge_vec[e * 3 + 1], ez = edge_vec[e * 3 + 2];
        float len = sqrtf(ex * ex + ey * ey + ez * ez);
        float rinv = 1.0f / (len + 1e-9f);
        float t = fminf(len, 3.99995f) * 128.0f;
        int ti = (int)t;
        float fr = t - (float)ti;
        unsigned fr16 = (unsigned)(fr * 65536.0f);
        if (fr16 > 65535u) fr16 = 65535u;
        float4 vv = {ex * rinv, ey * rinv, ez * rinv, __int_as_float(esrc[e])};
        *(float4*)(vec_csr + (size_t)p * 4) = vv;
        tifr[p] = (unsigned)ti | (fr16 << 16);
    }
}

// node fctp: 16 nodes/block; smem: [0,16K) w0 | [16K,32K) w1 | [32K,35K) sh
__device__ __forceinline__ void node_fctp_body(
    int blk, int path,
    const float* __restrict__ s, const float* __restrict__ v,
    const float* __restrict__ attr, const float* __restrict__ Wfp,
    float* __restrict__ sc_s, float* __restrict__ sc_v,
    float* __restrict__ xsv, int N, char* smem) {
    float* w0 = (float*)smem;
    float* w1 = (float*)(smem + 16384);
    float (*sh)[96] = (float(*)[96])(smem + 32768);
    int ln = threadIdx.x >> 5, w = threadIdx.x & 31;
    const float4* W0p = (const float4*)(Wfp + path * 8192);
    const float4* W1p = (const float4*)(Wfp + path * 8192 + 4096);
    for (int i = threadIdx.x; i < 1024; i += 256) {
        ((float4*)w0)[i] = W0p[i];
        ((float4*)w1)[i] = W1p[i];
    }
    for (int g = 0; g < 2; g++) {
        int n = blk * 16 + g * 8 + ln;
        bool valid = n < N;
        __syncthreads();
        if (valid) {
            if (path == 0) {
                sh[ln][w] = s[n * 32 + w];
            } else {
                sh[ln][w * 3 + 0] = v[n * 96 + w * 3 + 0];
                sh[ln][w * 3 + 1] = v[n * 96 + w * 3 + 1];
                sh[ln][w * 3 + 2] = v[n * 96 + w * 3 + 2];
            }
        }
        __syncthreads();
        if (!valid) continue;
        float4 at = *(const float4*)(attr + n * 4);
        if (path == 0) {
            float acc0 = 0.f, acc1 = 0.f;
            for (int u = 0; u < 32; u++) {
                float su = sh[ln][u];
                float4 W0v = *(const float4*)(w0 + u * 128 + w * 4);
                float4 W1v = *(const float4*)(w1 + u * 128 + w * 4);
                float d0 = at.x * W0v.x + at.y * W0v.y + at.z * W0v.z + at.w * W0v.w;
                float d1 = at.x * W1v.x + at.y * W1v.y + at.z * W1v.z + at.w * W1v.w;
                acc0 += su * d0;
                acc1 += su * d1;
            }
            sc_s[n * 32 + w] = acc0 * NORM128_F;
            xsv[(size_t)n * 128 + w * 4 + 3] = acc1 * NORM128_F;
        } else {
            float a00 = 0, a01 = 0, a02 = 0, a10 = 0, a11 = 0, a12 = 0;
            for (int u = 0; u < 32; u++) {
                float vu0 = sh[ln][u * 3 + 0];
                float vu1 = sh[ln][u * 3 + 1];
                float vu2 = sh[ln][u * 3 + 2];
                float4 W0v = *(const float4*)(w0 + u * 128 + w * 4);
                float4 W1v = *(const float4*)(w1 + u * 128 + w * 4);
                float d0 = at.x * W0v.x + at.y * W0v.y + at.z * W0v.z + at.w * W0v.w;
                float d1 = at.x * W1v.x + at.y * W1v.y + at.z * W1v.z + at.w * W1v.w;
                a00 += vu0 * d0; a01 += vu1 * d0; a02 += vu2 * d0;
                a10 += vu0 * d1; a11 += vu1 * d1; a12 += vu2 * d1;
            }
            sc_v[n * 96 + w * 3 + 0] = a00 * NORM128_F;
            sc_v[n * 96 + w * 3 + 1] = a01 * NORM128_F;
            sc_v[n * 96 + w * 3 + 2] = a02 * NORM128_F;
            float* xp = xsv + (size_t)n * 128 + w * 4;
            xp[0] = a10 * NORM128_F;
            xp[1] = a11 * NORM128_F;
            xp[2] = a12 * NORM128_F;
        }
    }
}

// ---------------------------------------------------------------- mega kernels
// tab blocks FIRST so the table generation starts immediately.
__global__ __launch_bounds__(256) void mega1(
    int nTab, int nInit, int nSetup,
    const float* __restrict__ x, float* __restrict__ s, float* __restrict__ v,
    const float* __restrict__ Wfc1, const float* __restrict__ Wfc2,
    const float* __restrict__ Wsc0, const float* __restrict__ Wl10,
    const float* __restrict__ Wsc1, const float* __restrict__ Wl11,
    const float* __restrict__ Wl20, const float* __restrict__ Wl21,
    float* __restrict__ Wfp, unsigned* __restrict__ Wupk,
    unsigned* __restrict__ tab,
    const int* __restrict__ edst, int* __restrict__ cnt, int N, int E) {
    __shared__ float sh_h[4][64];
    int b = blockIdx.x;
    if (b < nTab) { tab_gen_body(b, Wfc1, Wfc2, tab, sh_h); return; }
    b -= nTab;
    if (b < nInit) { init_sv_body(b, x, s, v, N); return; }
    b -= nInit;
    if (b < nSetup) {
        setup_weights_body(b, Wsc0, Wl10, Wsc1, Wl11, Wl20, Wl21, Wfp, Wupk);
        return;
    }
    b -= nSetup;
    csr_count_body(b, edst, cnt, E);
}

// Parallel CSR slot allocation: per-wave64 inclusive shfl-scan of cnt, one
// atomicAdd per wave for the base. Slot order across waves is arbitrary —
// every consumer is order-independent (per-node sums).
__global__ __launch_bounds__(256, 8) void csr_alloc(
    const int* __restrict__ cnt, int* __restrict__ off,
    int* __restrict__ cursor, int* __restrict__ gcur, int N) {
    int i = blockIdx.x * 256 + threadIdx.x;
    int lane = threadIdx.x & 63;
    int c = (i < N) ? cnt[i] : 0;
    int sc = c;
#pragma unroll
    for (int d = 1; d < 64; d <<= 1) {
        int t = __shfl_up(sc, d);
        if (lane >= d) sc += t;
    }
    int total = __shfl(sc, 63);
    int base = 0;
    if (lane == 0) base = atomicAdd(gcur, total);
    base = __shfl(base, 0);
    if (i < N) {
        int o = base + sc - c;      // exclusive position
        off[i] = o;
        cursor[i] = o;
    }
}

// csr_fill || fctp(layer0, both paths) || tab4 conversion
__global__ __launch_bounds__(256, 4) void mega2(
    int nFill, int nF,
    const int* __restrict__ edst, const int* __restrict__ esrc,
    const float* __restrict__ edge_vec, int* __restrict__ cursor,
    float* __restrict__ vec_csr, unsigned* __restrict__ tifr, int E,
    const float* __restrict__ s, const float* __restrict__ v,
    const float* __restrict__ attr, const float* __restrict__ Wfp,
    float* __restrict__ sc_s, float* __restrict__ sc_v,
    float* __restrict__ xsv, int N,
    const unsigned* __restrict__ tab, unsigned* __restrict__ tab4) {
    __shared__ __align__(16) char smem[35840];
    int b = blockIdx.x;
    if (b < nFill) {
        csr_fill_body(b, edst, esrc, edge_vec, cursor, vec_csr, tifr, E);
        return;
    }
    b -= nFill;
    if (b < 2 * nF) {
        node_fctp_body(b % nF, b / nF, s, v, attr, Wfp, sc_s, sc_v, xsv, N, smem);
        return;
    }
    b -= 2 * nF;
    tab4_body(b, tab, tab4);
}

// next-layer fctp (both paths) as a standalone dispatch
__global__ __launch_bounds__(256, 4) void fctp_only(
    int nF,
    const float* __restrict__ s, const float* __restrict__ v,
    const float* __restrict__ attr, const float* __restrict__ Wfp,
    float* __restrict__ sc_s, float* __restrict__ sc_v,
    float* __restrict__ xsv, int N) {
    __shared__ __align__(16) char smem[35840];
    node_fctp_body(blockIdx.x % nF, blockIdx.x / nF, s, v, attr, Wfp,
                   sc_s, sc_v, xsv, N, smem);
}

// ---------------------------------------------------------------- gather+update
// 2 nodes/block, 128 threads each (4 quarter-waves striding slots by 4).
// Edge weights from the delta-form tab4 (sqrt3 pre-folded into w2 column;
// vec_csr holds the UNIT edge vector); ti/fr packed into one dword per slot.
// Agg stays in LDS; update phase runs wave-parallel. No atomics anywhere.
// Resource footprint is tiny (VGPR 36, LDS 3KB) -> run 8 blocks/CU for
// full 32-wave occupancy (was 4 -> 52%).
__global__ __launch_bounds__(256, 8) void gather_update(
    const int* __restrict__ off, const int* __restrict__ cnt,
    const unsigned* __restrict__ tab4,
    const float* __restrict__ vec_csr, const unsigned* __restrict__ tifr,
    const float* __restrict__ xsv,
    const float* __restrict__ attr, const unsigned* __restrict__ Wupk,
    const float* __restrict__ sc_s, const float* __restrict__ sc_v,
    float* __restrict__ s, float* __restrict__ v, int N) {
    __shared__ float red[2][8][32];
    __shared__ float part[2][4][32];
    int pair = threadIdx.x >> 7;
    int node = blockIdx.x * 2 + pair;
    int ql = threadIdx.x & 127;
    int quarter = ql >> 5;
    int u = ql & 31;
    bool active = node < N;
    int o = 0, deg = 0;
    if (active) { o = off[node]; deg = cnt[node]; }
    float as0 = 0, as1 = 0;
    float av00 = 0, av01 = 0, av02 = 0, av10 = 0, av11 = 0, av12 = 0;

    auto body = [&](int slot) {
        size_t p = (size_t)slot;
        float4 vv = *(const float4*)(vec_csr + p * 4);   // unit0..2, src
        int src = __float_as_int(vv.w);
        unsigned tf = tifr[p];
        int ti = (int)(tf & 0xFFFFu);
        float fr = (float)(tf >> 16) * (1.0f / 65536.0f);
        uint4 tq = ((const uint4*)tab4)[((size_t)ti << 5) + u];
        float4 x4 = *(const float4*)(xsv + (size_t)src * 128 + u * 4);
        float wa = bf2f_lo(tq.x) + fr * bf2f_lo(tq.z);   // w0
        float wc = bf2f_hi(tq.x) + fr * bf2f_hi(tq.z);   // sqrt3*w2
        float wb = bf2f_lo(tq.y) + fr * bf2f_lo(tq.w);   // w1
        float wd = bf2f_hi(tq.y) + fr * bf2f_hi(tq.w);   // w3
        as0 += wa * x4.w;
        as1 += wb * (vv.x * x4.x + vv.y * x4.y + vv.z * x4.z);
        float tt = wc * x4.w;
        av00 += tt * vv.x;  av01 += tt * vv.y;  av02 += tt * vv.z;
        av10 += wd * x4.x; av11 += wd * x4.y; av12 += wd * x4.z;
    };

    int i = quarter;
    for (; i + 4 < deg; i += 8) { body(o + i); body(o + i + 4); }
    for (; i < deg; i += 4) body(o + i);

    as0 += __shfl_down(as0, 32);  as1 += __shfl_down(as1, 32);
    av00 += __shfl_down(av00, 32); av01 += __shfl_down(av01, 32); av02 += __shfl_down(av02, 32);
    av10 += __shfl_down(av10, 32); av11 += __shfl_down(av11, 32); av12 += __shfl_down(av12, 32);

    int lane = threadIdx.x & 63;
    int upper_wave = (threadIdx.x >> 6) & 1;
    if (upper_wave && lane < 32) {
        red[pair][0][u] = as0;  red[pair][1][u] = as1;
        red[pair][2][u] = av00; red[pair][3][u] = av01; red[pair][4][u] = av02;
        red[pair][5][u] = av10; red[pair][6][u] = av11; red[pair][7][u] = av12;
    }
    __syncthreads();
    if (!upper_wave && lane < 32) {
        // final scaled agg vector -> red
        red[pair][0][u] = (as0 + red[pair][0][u]) * INV_SQRTNN_F;   // agg_s[u]
        red[pair][1][u] = (as1 + red[pair][1][u]) * INV_SQRTNN_F;   // agg_s[32+u]
        red[pair][2][u] = (av00 + red[pair][2][u]) * INV_SQRTNN_F;  // agg_v[u][.]
        red[pair][3][u] = (av01 + red[pair][3][u]) * INV_SQRTNN_F;
        red[pair][4][u] = (av02 + red[pair][4][u]) * INV_SQRTNN_F;
        red[pair][5][u] = (av10 + red[pair][5][u]) * INV_SQRTNN_F;  // agg_v[32+u][.]
        red[pair][6][u] = (av11 + red[pair][6][u]) * INV_SQRTNN_F;
        red[pair][7][u] = (av12 + red[pair][7][u]) * INV_SQRTNN_F;
    }
    __syncthreads();

    // ---- update phase: all 128 threads/node; quarter q covers uu in
    // [q*16,(q+1)*16); shfl+LDS reduce the 4 partials; lower-wave finalizes.
    {
        int half = quarter >> 1;            // uu<32 for q0,q1; uu>=32 for q2,q3
        int ub = (quarter & 1) * 16;        // within-half base
        int w = u;
        float4 at = {0.f, 0.f, 0.f, 0.f};
        if (active) at = *(const float4*)(attr + node * 4);
        const float* rs = red[pair][half];
        const float* r0 = red[pair][2 + 3 * half];
        const float* r1 = red[pair][3 + 3 * half];
        const float* r2 = red[pair][4 + 3 * half];
        float pacc = 0.f, pa0 = 0.f, pa1 = 0.f, pa2 = 0.f;
#pragma unroll
        for (int k = 0; k < 16; k++) {
            int j = ub + k;                 // index within half, 0..31
            float gs = rs[j], g0 = r0[j], g1 = r1[j], g2 = r2[j];
            uint4 pv = *(const uint4*)(Wupk + (half * 32 + j) * 128 + w * 4);
            float w20x = bf2f_lo(pv.x), w21x = bf2f_hi(pv.x);
            float w20y = bf2f_lo(pv.y), w21y = bf2f_hi(pv.y);
            float w20z = bf2f_lo(pv.z), w21z = bf2f_hi(pv.z);
            float w20w = bf2f_lo(pv.w), w21w = bf2f_hi(pv.w);
            float d0 = at.x * w20x + at.y * w20y + at.z * w20z + at.w * w20w;
            float d1 = at.x * w21x + at.y * w21y + at.z * w21z + at.w * w21w;
            pacc += gs * d0;
            pa0 += g0 * d1; pa1 += g1 * d1; pa2 += g2 * d1;
        }
        pacc += __shfl_down(pacc, 32);
        pa0 += __shfl_down(pa0, 32);
        pa1 += __shfl_down(pa1, 32);
        pa2 += __shfl_down(pa2, 32);
        if (upper_wave && lane < 32) {
            part[pair][0][u] = pacc;
            part[pair][1][u] = pa0;
            part[pair][2][u] = pa1;
            part[pair][3][u] = pa2;
        }
        __syncthreads();
        if (active && !upper_wave && lane < 32) {
            pacc += part[pair][0][u];
            pa0 += part[pair][1][u];
            pa1 += part[pair][2][u];
            pa2 += part[pair][3][u];
            float os = pacc * NORM256_F;
            float sn = C_S_F * sc_s[node * 32 + w] + C_X_F * os;
            float sig = 1.0f / (1.0f + __expf(-sn));
            s[node * 32 + w] += sn * sig;   // silu(sn)
            float ov0 = pa0 * NORM256_F, ov1 = pa1 * NORM256_F, ov2 = pa2 * NORM256_F;
            v[node * 96 + w * 3 + 0] += (C_S_F * sc_v[node * 96 + w * 3 + 0] + C_X_F * ov0) * sig;
            v[node * 96 + w * 3 + 1] += (C_S_F * sc_v[node * 96 + w * 3 + 1] + C_X_F * ov1) * sig;
            v[node * 96 + w * 3 + 2] += (C_S_F * sc_v[node * 96 + w * 3 + 2] + C_X_F * ov2) * sig;
        }
    }
}

// ---------------------------------------------------------------- readout
__global__ __launch_bounds__(256, 8) void readout(
    const float* __restrict__ s, const float* __restrict__ attr,
    const float* __restrict__ Wread, const int* __restrict__ batch,
    float* __restrict__ out, int N, float pool_scale) {
    __shared__ float wr[2048];
    __shared__ float red[NGRAPH * 16];
    for (int i = threadIdx.x; i < 2048; i += 256) wr[i] = Wread[i];
    if (threadIdx.x < NGRAPH * 16) red[threadIdx.x] = 0.f;
    __syncthreads();
    int ln = threadIdx.x >> 4, w = threadIdx.x & 15;
    for (int g = 0; g < 4; g++) {
        int n = blockIdx.x * 64 + g * 16 + ln;
        if (n < N) {
            float4 at = *(const float4*)(attr + n * 4);
            float fa[4] = {at.x, at.y, at.z, at.w};
            float acc = 0.f;
            for (int u = 0; u < 32; u++) {
                float su = s[n * 32 + u];
                int base = u * 64 + w;
#pragma unroll
                for (int a = 0; a < 4; a++) acc += su * fa[a] * wr[base + a * 16];
            }
            atomicAdd(&red[batch[n] * 16 + w], acc);
        }
    }
    __syncthreads();
    if (threadIdx.x < NGRAPH * 16) {
        float val = red[threadIdx.x];
        if (val != 0.f)
            atomicAdd(&out[threadIdx.x], val * NORM128_F * pool_scale);
    }
}

// ---------------------------------------------------------------- launch
extern "C" void kernel_launch(void* const* d_in, const int* in_sizes, int n_in,
                              void* d_out, int out_size, void* d_ws, size_t ws_size,
                              hipStream_t stream) {
    const float* x        = (const float*)d_in[0];
    const float* nattr    = (const float*)d_in[1];
    const float* edge_vec = (const float*)d_in[2];
    const int*   batch    = (const int*)d_in[3];
    const int*   esrc     = (const int*)d_in[4];
    const int*   edst     = (const int*)d_in[5];
    const float* Wsc0  = (const float*)d_in[6];
    const float* Wsc1  = (const float*)d_in[7];
    const float* Wl10  = (const float*)d_in[8];
    const float* Wl11  = (const float*)d_in[9];
    const float* Wfc1  = (const float*)d_in[10];
    const float* Wfc2  = (const float*)d_in[11];
    const float* Wl20  = (const float*)d_in[12];
    const float* Wl21  = (const float*)d_in[13];
    const float* Wread = (const float*)d_in[14];

    int N = in_sizes[0] / (MUL * 4);
    int E = in_sizes[2] / 3;

    float* p = (float*)d_ws;
    float* vec_csr = p; p += (size_t)E * 4;     // {unit0,unit1,unit2,src-bits}
    unsigned* tifr = (unsigned*)p; p += ((size_t)E + 3) & ~(size_t)3;  // {ti|fr16}/slot
    unsigned* tab = (unsigned*)p; p += 2 * NT * 64;  // w(len) tables, packed bf16
    unsigned* tab4 = (unsigned*)p; p += 2 * 512 * 32 * 4;  // delta-form tables
    float* Wfp    = p; p += 32768;              // 2 layers x 4 matrices x 4096
    unsigned* Wupk = (unsigned*)p; p += 16384;  // 2 layers x 8192 packed pair dwords
    float* s_buf  = p; p += (size_t)N * 32;
    float* v_buf  = p; p += (size_t)N * 96;
    float* sc_s   = p; p += (size_t)N * 32;
    float* sc_v   = p; p += (size_t)N * 96;
    float* xsv    = p; p += (size_t)N * 128;    // {xv0,xv1,xv2,xs} per (n,u)
    int* cnt     = (int*)p; p += N;
    int* off     = (int*)p; p += N;
    int* cursor  = (int*)p; p += N;
    int* gcur    = (int*)p; p += 1;

    hipMemsetAsync(d_out, 0, (size_t)out_size * sizeof(float), stream);
    hipMemsetAsync(cnt, 0, ((size_t)3 * N + 1) * sizeof(int), stream);  // cnt..gcur

    int nTab   = (2 * NT + 3) / 4;              // 4 rows per block
    int nInit  = (N * 128 + 255) / 256;
    int nSetup = 192;
    int nCount = (E + 255) / 256;
    mega1<<<nTab + nInit + nSetup + nCount, 256, 0, stream>>>(
        nTab, nInit, nSetup, x, s_buf, v_buf,
        Wfc1, Wfc2, Wsc0, Wl10, Wsc1, Wl11, Wl20, Wl21,
        Wfp, Wupk, tab, edst, cnt, N, E);

    csr_alloc<<<(N + 255) / 256, 256, 0, stream>>>(cnt, off, cursor, gcur, N);

    int nFill = (E + 255) / 256;
    int nF = (N + 15) / 16;
    int nConv = (2 * 512 * 32 + 255) / 256;     // tab4 converter blocks
    mega2<<<nFill + 2 * nF + nConv, 256, 0, stream>>>(
        nFill, nF, edst, esrc, edge_vec, cursor, vec_csr, tifr, E,
        s_buf, v_buf, nattr, Wfp, sc_s, sc_v, xsv, N, tab, tab4);

    int nG = (N + 1) / 2;

    // ---- layer 0: gather+update fused, then next-layer fctp
    gather_update<<<nG, 256, 0, stream>>>(
        off, cnt, tab4, vec_csr, tifr, xsv, nattr, Wupk,
        sc_s, sc_v, s_buf, v_buf, N);
    fctp_only<<<2 * nF, 256, 0, stream>>>(
        nF, s_buf, v_buf, nattr, Wfp + 16384, sc_s, sc_v, xsv, N);

    // ---- layer 1: gather+update fused (no further fctp)
    gather_update<<<nG, 256, 0, stream>>>(
        off, cnt, tab4 + 512 * 32 * 4, vec_csr, tifr, xsv, nattr, Wupk + 8192,
        sc_s, sc_v, s_buf, v_buf, N);

    float pool_scale = (float)(1.0 / sqrt((double)N / (double)NGRAPH));
    readout<<<(N + 63) / 64, 256, 0, stream>>>(
        s_buf, nattr, Wread, batch, (float*)d_out, N, pool_scale);
}